// Round 14
// baseline (1244.752 us; speedup 1.0000x reference)
//
#include <hip/hip_runtime.h>
#include <hip/hip_bf16.h>
#include <math.h>

typedef _Float16 f16;
typedef f16   f16x8 __attribute__((ext_vector_type(8)));
typedef float f32x4 __attribute__((ext_vector_type(4)));
typedef unsigned short ushort_t;

#define DIM   768
#define HEADS 12
#define DH    64
#define MLP_  3072
#define NTOK  2048
#define SEQ   1024
#define WELTS 7077888   // per-layer converted weight elements (Wq+Wkv+Wo+W1+W2)

__device__ __forceinline__ ushort_t h2u(f16 h){ return __builtin_bit_cast(ushort_t, h); }
__device__ __forceinline__ unsigned pk2h(float a, float b){
  return (unsigned)h2u((f16)a) | ((unsigned)h2u((f16)b) << 16);
}
__device__ __forceinline__ void gload16(const void* g, void* l){
  __builtin_amdgcn_global_load_lds(
      (const __attribute__((address_space(1))) void*)g,
      (__attribute__((address_space(3))) void*)l, 16, 0, 0);
}
__device__ __forceinline__ float wred_sum(float v){
  #pragma unroll
  for (int o = 32; o > 0; o >>= 1) v += __shfl_xor(v, o);
  return v;
}

// ---------- weight convert body: W[K][N] f32 -> Wt [N][K] f16 ----------------
__device__ __forceinline__ void convert_body(
    int bid, const float* __restrict__ Wq, const float* __restrict__ Wkv,
    const float* __restrict__ Wo, const float* __restrict__ W1,
    const float* __restrict__ W2, int layer, int wp_only,
    f16* __restrict__ th)
{
  const float* src; int K, N; size_t ooff; int t;
  if (wp_only){ src = Wq; K = 768; N = 768; ooff = 0; t = bid; }
  else if (bid < 144) { src = Wq;  K = 768;  N = 768;  ooff = 0;       t = bid; }
  else if (bid < 432) { src = Wkv; K = 768;  N = 1536; ooff = 589824;  t = bid - 144; }
  else if (bid < 576) { src = Wo;  K = 768;  N = 768;  ooff = 1769472; t = bid - 432; }
  else if (bid < 1152){ src = W1;  K = 768;  N = 3072; ooff = 2359296; t = bid - 576; }
  else                { src = W2;  K = 3072; N = 768;  ooff = 4718592; t = bid - 1152; }
  if (!wp_only) src += (size_t)layer * K * N;
  int ntn = N >> 6;
  int tk = t / ntn, tn = t % ntn;
  int k0 = tk * 64, n0 = tn * 64;

  __shared__ unsigned lp[32][66];
  const int tid = threadIdx.x;
  #pragma unroll
  for (int p = 0; p < 2; p++){
    int rp = p * 16 + (tid >> 4);
    int c  = (tid & 15) * 4;
    const float* s0 = src + (size_t)(k0 + 2 * rp) * N + n0 + c;
    float4 a = *(const float4*)s0;
    float4 b = *(const float4*)(s0 + N);
    unsigned u0 = pk2h(a.x, b.x), u1 = pk2h(a.y, b.y);
    unsigned u2 = pk2h(a.z, b.z), u3 = pk2h(a.w, b.w);
    *(uint4*)&lp[rp][c] = make_uint4(u0, u1, u2, u3);
  }
  __syncthreads();
  #pragma unroll
  for (int p = 0; p < 2; p++){
    int n = p * 32 + (tid >> 3);
    int q = tid & 7;
    unsigned u[4];
    #pragma unroll
    for (int j = 0; j < 4; j++) u[j] = lp[q * 4 + j][n];
    *(uint4*)(th + ooff + (size_t)(n0 + n) * K + k0 + q * 8)
        = make_uint4(u[0], u[1], u[2], u[3]);
  }
}

__global__ __launch_bounds__(256) void convert_w_kernel(
    const float* __restrict__ Wq, const float* __restrict__ Wkv,
    const float* __restrict__ Wo, const float* __restrict__ W1,
    const float* __restrict__ W2, int layer, int wp_only,
    f16* __restrict__ th)
{
  convert_body(blockIdx.x, Wq, Wkv, Wo, W1, W2, layer, wp_only, th);
}

// ------------- big GEMM body: 128x128 block, 4 waves of 64x64, BK=64 ---------
// A read DIRECT global->VGPR (L1/L2-hot panel, 16x64B segments/load);
// B staged via pre-swizzled global_load_lds into 16KB LDS (single-buffer).
// mode 1: f16 gelu(acc+bias) -> Cq[N]
// mode 2: qkv epilogue (fused qk-rmsnorm, gammas folded into Q)
// mode 3: split-K f16 partial -> Cq + z*NTOK*N
__device__ __forceinline__ void gemm_big_body(
    int bid, int bz, int nz,
    const f16* __restrict__ Aq, const f16* __restrict__ Bw,
    const float* __restrict__ bias,
    f16* __restrict__ Cq,
    f16* __restrict__ Qh, f16* __restrict__ Kt, f16* __restrict__ Vt,
    const float* __restrict__ qgam, const float* __restrict__ kgam,
    int N, int K, int nbx, int mode)
{
  __shared__ __align__(16) f16 sB[128 * 64];
  const int tid = threadIdx.x;
  const int wid = tid >> 6, lane = tid & 63;
  const int nwg = nbx << 4;
  const int swz = (bid & 7) * (nwg >> 3) + (bid >> 3);
  const int by = swz & 15, bx = swz >> 4;
  const int brow = by << 7, bcol = bx << 7;
  const int m2 = wid & 1, n2 = wid >> 1;
  const int fr = lane & 15, fq = lane >> 4;
  const int Kc = K / nz;
  const int kbase = bz * Kc;
  const int nk = Kc >> 6;

  const f16* pA = Aq + (size_t)brow * K + kbase;
  const f16* pB = Bw + (size_t)bcol * K + kbase;
  const int arow0 = m2 * 64 + fr;

  f32x4 acc[4][4] = {};

  for (int ks = 0; ks < nk; ks++){
    const int k0 = ks << 6;
    if (ks) __syncthreads();
    #pragma unroll
    for (int i = 0; i < 4; i++){
      int idx = tid + i * 256;
      int r = idx >> 3, c = idx & 7;
      int gc = c ^ (r & 7);
      gload16(pB + (size_t)r * K + k0 + gc * 8, &sB[idx * 8]);
    }
    // A fragments direct from global (unswizzled), both k-halves
    f16x8 a2[2][4];
    #pragma unroll
    for (int s = 0; s < 2; s++)
      #pragma unroll
      for (int m = 0; m < 4; m++)
        a2[s][m] = *(const f16x8*)(pA + (size_t)(arow0 + m * 16) * K + k0 + s * 32 + fq * 8);
    __syncthreads();
    #pragma unroll
    for (int s = 0; s < 2; s++){
      f16x8 b[4];
      #pragma unroll
      for (int n = 0; n < 4; n++){
        int r = n2 * 64 + n * 16 + fr;
        int ch = (s * 4 + fq) ^ (r & 7);
        b[n] = *(const f16x8*)(&sB[r * 64 + ch * 8]);
      }
      #pragma unroll
      for (int m = 0; m < 4; m++)
        #pragma unroll
        for (int n = 0; n < 4; n++)
          acc[m][n] = __builtin_amdgcn_mfma_f32_16x16x32_f16(a2[s][m], b[n], acc[m][n], 0, 0, 0);
    }
  }

  // epilogue: D layout col=lane&15, row=(lane>>4)*4+i
  if (mode == 2){
    const int hbase = bcol + n2 * 64;   // wave-uniform, 64-aligned head block
    if (hbase < 768){
      float gp[4];
      #pragma unroll
      for (int n = 0; n < 4; n++){
        int col = hbase + n * 16 + fr;
        gp[n] = qgam[col] * kgam[col];
      }
      #pragma unroll
      for (int m = 0; m < 4; m++)
        #pragma unroll
        for (int i = 0; i < 4; i++){
          float s = 0.f;
          #pragma unroll
          for (int n = 0; n < 4; n++) s += acc[m][n][i] * acc[m][n][i];
          s += __shfl_xor(s, 1); s += __shfl_xor(s, 2);
          s += __shfl_xor(s, 4); s += __shfl_xor(s, 8);
          float f = 8.f / fmaxf(sqrtf(s), 1e-12f);
          int row = brow + m2 * 64 + m * 16 + (fq << 2) + i;
          #pragma unroll
          for (int n = 0; n < 4; n++)
            Qh[(size_t)row * 768 + hbase + n * 16 + fr] = (f16)(acc[m][n][i] * f * gp[n]);
        }
    } else if (hbase < 1536){
      int hh = (hbase - 768) >> 6;
      #pragma unroll
      for (int m = 0; m < 4; m++)
        #pragma unroll
        for (int i = 0; i < 4; i++){
          float s = 0.f;
          #pragma unroll
          for (int n = 0; n < 4; n++) s += acc[m][n][i] * acc[m][n][i];
          s += __shfl_xor(s, 1); s += __shfl_xor(s, 2);
          s += __shfl_xor(s, 4); s += __shfl_xor(s, 8);
          float f = 8.f / fmaxf(sqrtf(s), 1e-12f);
          int row = brow + m2 * 64 + m * 16 + (fq << 2) + i;
          int bq = row >> 10, tok = row & 1023;
          #pragma unroll
          for (int n = 0; n < 4; n++)
            Kt[((size_t)(bq * 12 + hh) * 1024 + tok) * 64 + n * 16 + fr]
                = (f16)(acc[m][n][i] * f);
        }
    } else {
      int hh = (hbase - 1536) >> 6;
      #pragma unroll
      for (int n = 0; n < 4; n++){
        int dd = n * 16 + fr;
        #pragma unroll
        for (int m = 0; m < 4; m++){
          int row0 = brow + m2 * 64 + m * 16 + (fq << 2);
          int bq = row0 >> 10, tok0 = row0 & 1023;
          ushort4 sv;
          sv.x = h2u((f16)acc[m][n][0]); sv.y = h2u((f16)acc[m][n][1]);
          sv.z = h2u((f16)acc[m][n][2]); sv.w = h2u((f16)acc[m][n][3]);
          *(ushort4*)(Vt + ((size_t)((bq * 12 + hh) * 64 + dd)) * 1024 + tok0) = sv;
        }
      }
    }
  } else if (mode == 1){
    #pragma unroll
    for (int n = 0; n < 4; n++){
      int col = bcol + n2 * 64 + n * 16 + fr;
      float bv = bias[col];
      #pragma unroll
      for (int m = 0; m < 4; m++){
        int row0 = brow + m2 * 64 + m * 16 + (fq << 2);
        #pragma unroll
        for (int i = 0; i < 4; i++){
          float v = acc[m][n][i] + bv;
          float ge = 0.5f * v * (1.f + erff(v * 0.70710678118654752f));
          Cq[(size_t)(row0 + i) * N + col] = (f16)ge;
        }
      }
    }
  } else {  // mode 3: f16 split-K partials
    f16* P = Cq + (size_t)bz * ((size_t)NTOK * N);
    #pragma unroll
    for (int n = 0; n < 4; n++){
      int col = bcol + n2 * 64 + n * 16 + fr;
      #pragma unroll
      for (int m = 0; m < 4; m++){
        int row0 = brow + m2 * 64 + m * 16 + (fq << 2);
        #pragma unroll
        for (int i = 0; i < 4; i++)
          P[(size_t)(row0 + i) * N + col] = (f16)acc[m][n][i];
      }
    }
  }
}

__global__ __launch_bounds__(256) void gemm_big(
    const f16* __restrict__ Aq, const f16* __restrict__ Bw,
    const float* __restrict__ bias,
    f16* __restrict__ Cq,
    f16* __restrict__ Qh, f16* __restrict__ Kt, f16* __restrict__ Vt,
    const float* __restrict__ qgam, const float* __restrict__ kgam,
    int N, int K, int nbx, int mode)
{
  gemm_big_body(blockIdx.x, blockIdx.z, (int)gridDim.z,
                Aq, Bw, bias, Cq, Qh, Kt, Vt, qgam, kgam, N, K, nbx, mode);
}

// ------ merged: qkv projection (blocks 0-287) + next-layer convert (288+) ----
__global__ __launch_bounds__(256) void qkvconv_kernel(
    const f16* __restrict__ Aq, const f16* __restrict__ Bw,
    f16* __restrict__ Qh, f16* __restrict__ Kt, f16* __restrict__ Vt,
    const float* __restrict__ qgam, const float* __restrict__ kgam,
    const float* __restrict__ Wq, const float* __restrict__ Wkv,
    const float* __restrict__ Wo, const float* __restrict__ W1,
    const float* __restrict__ W2, int nlayer, f16* __restrict__ thn)
{
  if (blockIdx.x < 288)
    gemm_big_body((int)blockIdx.x, 0, 1, Aq, Bw, nullptr, nullptr,
                  Qh, Kt, Vt, qgam, kgam, 3 * DIM, DIM, 18, 2);
  else if (nlayer >= 0)
    convert_body((int)blockIdx.x - 288, Wq, Wkv, Wo, W1, W2, nlayer, 0, thn);
}

// ------------- small GEMM (64x64 block, 4 waves of 32x32): f32 out -----------
__global__ __launch_bounds__(256) void gemm_small(
    const f16* __restrict__ Aq, const f16* __restrict__ Bw,
    const float* __restrict__ bias, const float* __restrict__ res,
    float* __restrict__ C, int N, int K, int nbx)
{
  __shared__ __align__(16) f16 sA[2][64 * 64];
  __shared__ __align__(16) f16 sB[2][64 * 64];
  const int tid = threadIdx.x;
  const int wid = tid >> 6, lane = tid & 63;
  const int nwg = nbx << 5;
  const int bid = blockIdx.x;
  const int swz = (bid & 7) * (nwg >> 3) + (bid >> 3);
  const int by = swz & 31, bx = swz >> 5;
  const int brow = by << 6, bcol = bx << 6;
  const int m2 = wid & 1, n2 = wid >> 1;
  const int fr = lane & 15, fq = lane >> 4;
  const int nk = K >> 6;

  const f16* pA = Aq + (size_t)brow * K;
  const f16* pB = Bw + (size_t)bcol * K;

  f32x4 acc[2][2] = {};

  auto STAGE = [&](int buf, int ks){
    const int k0 = ks << 6;
    #pragma unroll
    for (int i = 0; i < 2; i++){
      int idx = tid + i * 256;
      int r = idx >> 3, c = idx & 7;
      int gc = c ^ (r & 7);
      gload16(pA + (size_t)r * K + k0 + gc * 8, &sA[buf][idx * 8]);
      gload16(pB + (size_t)r * K + k0 + gc * 8, &sB[buf][idx * 8]);
    }
  };

  STAGE(0, 0);
  __syncthreads();
  int cur = 0;
  for (int ks = 0; ks < nk; ks++){
    if (ks + 1 < nk) STAGE(cur ^ 1, ks + 1);
    #pragma unroll
    for (int s = 0; s < 2; s++){
      f16x8 a[2], b[2];
      #pragma unroll
      for (int m = 0; m < 2; m++){
        int r = m2 * 32 + m * 16 + fr;
        int ch = (s * 4 + fq) ^ (r & 7);
        a[m] = *(const f16x8*)(&sA[cur][r * 64 + ch * 8]);
      }
      #pragma unroll
      for (int n = 0; n < 2; n++){
        int r = n2 * 32 + n * 16 + fr;
        int ch = (s * 4 + fq) ^ (r & 7);
        b[n] = *(const f16x8*)(&sB[cur][r * 64 + ch * 8]);
      }
      #pragma unroll
      for (int m = 0; m < 2; m++)
        #pragma unroll
        for (int n = 0; n < 2; n++)
          acc[m][n] = __builtin_amdgcn_mfma_f32_16x16x32_f16(a[m], b[n], acc[m][n], 0, 0, 0);
    }
    __syncthreads();
    cur ^= 1;
  }

  #pragma unroll
  for (int n = 0; n < 2; n++){
    int col = bcol + n2 * 32 + n * 16 + fr;
    float bv = bias ? bias[col] : 0.f;
    #pragma unroll
    for (int m = 0; m < 2; m++){
      int row0 = brow + m2 * 32 + m * 16 + (fq << 2);
      #pragma unroll
      for (int i = 0; i < 4; i++){
        float v = acc[m][n][i] + bv;
        size_t o = (size_t)(row0 + i) * N + col;
        if (res) v += res[o];
        C[o] = v;
      }
    }
  }
}

// ------- fused (optional 4-way f16 split-K reduce + badd + residual) + LN ----
__global__ __launch_bounds__(256) void lnred_kernel(
    float* __restrict__ x, const f16* __restrict__ p, const float* __restrict__ badd,
    int npart, const float* __restrict__ g, f16* __restrict__ yq, float* __restrict__ yf)
{
  int wid = threadIdx.x >> 6, lane = threadIdx.x & 63;
  int row = blockIdx.x * 4 + wid;
  float* xr = x + (size_t)row * DIM;
  float v[12]; float s = 0.f;
  if (npart){
    #pragma unroll
    for (int d = 0; d < 12; d++){
      int c = d * 64 + lane;
      float t = xr[c] + badd[c];
      #pragma unroll
      for (int j = 0; j < 4; j++)
        t += (float)p[(size_t)j * (NTOK * DIM) + (size_t)row * DIM + c];
      xr[c] = t; v[d] = t; s += t;
    }
  } else {
    #pragma unroll
    for (int d = 0; d < 12; d++){ v[d] = xr[d * 64 + lane]; s += v[d]; }
  }
  s = wred_sum(s);
  float mean = s * (1.f / 768.f);
  float q2 = 0.f;
  #pragma unroll
  for (int d = 0; d < 12; d++){ float t = v[d] - mean; q2 += t * t; }
  q2 = wred_sum(q2);
  float rstd = rsqrtf(q2 * (1.f / 768.f) + 1e-5f);
  size_t base = (size_t)row * DIM;
  #pragma unroll
  for (int d = 0; d < 12; d++){
    float y = (v[d] - mean) * rstd * g[d * 64 + lane];
    if (yq) yq[base + d * 64 + lane] = (f16)y;
    else    yf[base + d * 64 + lane] = y;
  }
}

// ---------------- pos-embed add -> f16 ---------------------------------------
__global__ __launch_bounds__(256) void posadd_kernel(
    const float* __restrict__ patches, const int* __restrict__ hi,
    const int* __restrict__ wi, const float* __restrict__ ph,
    const float* __restrict__ pw, f16* __restrict__ oq)
{
  int idx = blockIdx.x * 256 + threadIdx.x;
  int tok = idx / 192, cv = idx % 192;
  float4 p = ((const float4*)patches)[idx];
  float4 a = *(const float4*)(ph + (size_t)hi[tok] * DIM + cv * 4);
  float4 b = *(const float4*)(pw + (size_t)wi[tok] * DIM + cv * 4);
  ushort4 o;
  o.x = h2u((f16)(p.x + a.x + b.x)); o.y = h2u((f16)(p.y + a.y + b.y));
  o.z = h2u((f16)(p.z + a.z + b.z)); o.w = h2u((f16)(p.w + a.w + b.w));
  ((ushort4*)oq)[idx] = o;
}

// ---------------- segment ranges from sorted image_ids -----------------------
__global__ void seg_kernel(const int* __restrict__ ids, int2* __restrict__ segs)
{
  int i = blockIdx.x * 256 + threadIdx.x;
  int b = blockIdx.y;
  const int* row = ids + b * SEQ;
  int v = row[i];
  int lo = 0, hi = SEQ;
  while (lo < hi){ int mid = (lo + hi) >> 1; if (row[mid] <  v) lo = mid + 1; else hi = mid; }
  int s = lo;
  lo = 0; hi = SEQ;
  while (lo < hi){ int mid = (lo + hi) >> 1; if (row[mid] <= v) lo = mid + 1; else hi = mid; }
  segs[b * SEQ + i] = make_int2(s, lo);
}

// --------- MFMA flash attention over segments (all-f16, KVBLK=64) ------------
__global__ __launch_bounds__(256) void attn_kernel(
    const f16* __restrict__ qh, const f16* __restrict__ ktp,
    const f16* __restrict__ vt, const int2* __restrict__ segs,
    f16* __restrict__ oq)
{
  __shared__ __align__(16) ushort_t Kq[64 * 64];    // 8 KB, XOR-swizzled rows
  __shared__ __align__(16) ushort_t Vl[64 * 72];    // 9 KB, [d][key] stride 144B

  const int tid = threadIdx.x;
  const int w = tid >> 6, lane = tid & 63;
  const int q15 = lane & 15, kg = lane >> 4;
  const int bh = blockIdx.x, b = bh / 12, h = bh % 12;
  const int qt = blockIdx.y;
  const int qrow = qt * 64 + w * 16 + q15;
  const size_t qtok = (size_t)b * SEQ + qrow;

  const f16* qp = qh + qtok * DIM + h * 64 + kg * 8;
  f16x8 qf[2];
  qf[0] = *(const f16x8*)(qp);
  qf[1] = *(const f16x8*)(qp + 32);

  const int2 se  = segs[qtok];
  const int2 se0 = segs[(size_t)b * SEQ + qt * 64];
  const int2 se1 = segs[(size_t)b * SEQ + qt * 64 + 63];
  const int klo = se0.x & ~63, khi = se1.y;

  float m = -3.0e38f, l = 0.f;
  f32x4 oacc[4] = {};

  const f16* kbase = ktp + (size_t)bh * 1024 * 64;
  const int vd = tid >> 2, vc0 = tid & 3;

  for (int kt0 = klo; kt0 < khi; kt0 += 64){
    #pragma unroll
    for (int i = 0; i < 2; i++){
      int idx = tid + i * 256;
      int r = idx >> 3, c = idx & 7;
      int gc = c ^ (r & 7);
      gload16(kbase + (size_t)(kt0 + r) * 64 + gc * 8, Kq + idx * 8);
    }
    #pragma unroll
    for (int p2 = 0; p2 < 2; p2++){
      int chunk = vc0 + p2 * 4;
      uint4 vv = *(const uint4*)(vt + ((size_t)bh * 64 + vd) * SEQ + kt0 + chunk * 8);
      *(uint4*)((char*)Vl + vd * 144 + chunk * 16) = vv;
    }
    __syncthreads();

    f32x4 s[4] = {};
    #pragma unroll
    for (int dh2 = 0; dh2 < 2; dh2++){
      #pragma unroll
      for (int khf = 0; khf < 4; khf++){
        int row = khf * 16 + q15;
        unsigned off = ((unsigned)row << 7) + ((unsigned)(dh2 * 4 + kg) << 4);
        off ^= (unsigned)(row & 7) << 4;
        f16x8 kf = *(const f16x8*)((const char*)Kq + off);
        s[khf] = __builtin_amdgcn_mfma_f32_16x16x32_f16(kf, qf[dh2], s[khf], 0, 0, 0);
      }
    }

    float p[16]; float tmax = -3.0e38f;
    #pragma unroll
    for (int khf = 0; khf < 4; khf++)
      #pragma unroll
      for (int i = 0; i < 4; i++){
        int key = kt0 + khf * 16 + kg * 4 + i;
        bool val = (key >= se.x) && (key < se.y);
        float sv = val ? s[khf][i] : -3.0e38f;
        p[khf * 4 + i] = sv;
        tmax = fmaxf(tmax, sv);
      }
    tmax = fmaxf(tmax, __shfl_xor(tmax, 16));
    tmax = fmaxf(tmax, __shfl_xor(tmax, 32));
    float mnew = fmaxf(m, tmax);
    float sc = __expf(m - mnew);
    float psum = 0.f;
    #pragma unroll
    for (int j = 0; j < 16; j++){
      float pv = (p[j] > -1.0e38f) ? __expf(p[j] - mnew) : 0.f;
      p[j] = pv; psum += pv;
    }
    psum += __shfl_xor(psum, 16);
    psum += __shfl_xor(psum, 32);
    l = l * sc + psum;
    m = mnew;
    #pragma unroll
    for (int dt = 0; dt < 4; dt++) oacc[dt] *= sc;

    int s0l = q15 + ((kg & 1) << 5);
    int s1l = s0l + 16;
    bool hih = kg >= 2;
    unsigned uA0 = pk2h(p[0],  p[1]),  uA1 = pk2h(p[2],  p[3]);
    unsigned uA2 = pk2h(p[4],  p[5]),  uA3 = pk2h(p[6],  p[7]);
    unsigned uB0 = pk2h(p[8],  p[9]),  uB1 = pk2h(p[10], p[11]);
    unsigned uB2 = pk2h(p[12], p[13]), uB3 = pk2h(p[14], p[15]);
    unsigned a0 = __shfl(uA0, s0l), b0 = __shfl(uA1, s0l);
    unsigned a1 = __shfl(uA0, s1l), b1 = __shfl(uA1, s1l);
    unsigned c0 = __shfl(uA2, s0l), d0 = __shfl(uA3, s0l);
    unsigned c1 = __shfl(uA2, s1l), d1 = __shfl(uA3, s1l);
    f16x8 pfA = __builtin_bit_cast(f16x8,
        make_uint4(hih ? c0 : a0, hih ? d0 : b0, hih ? c1 : a1, hih ? d1 : b1));
    unsigned e0 = __shfl(uB0, s0l), f0 = __shfl(uB1, s0l);
    unsigned e1 = __shfl(uB0, s1l), f1 = __shfl(uB1, s1l);
    unsigned g0 = __shfl(uB2, s0l), h0 = __shfl(uB3, s0l);
    unsigned g1 = __shfl(uB2, s1l), h1 = __shfl(uB3, s1l);
    f16x8 pfB = __builtin_bit_cast(f16x8,
        make_uint4(hih ? g0 : e0, hih ? h0 : f0, hih ? g1 : e1, hih ? h1 : f1));

    #pragma unroll
    for (int dt = 0; dt < 4; dt++){
      const char* vb = (const char*)Vl + (dt * 16 + q15) * 144 + kg * 16;
      f16x8 vfA = *(const f16x8*)vb;
      f16x8 vfB = *(const f16x8*)(vb + 64);
      oacc[dt] = __builtin_amdgcn_mfma_f32_16x16x32_f16(vfA, pfA, oacc[dt], 0, 0, 0);
      oacc[dt] = __builtin_amdgcn_mfma_f32_16x16x32_f16(vfB, pfB, oacc[dt], 0, 0, 0);
    }
    __syncthreads();
  }

  float rl = 1.f / l;
  size_t obase = qtok * DIM + h * 64;
  #pragma unroll
  for (int dt = 0; dt < 4; dt++){
    ushort4 hs;
    hs.x = h2u((f16)(oacc[dt][0] * rl)); hs.y = h2u((f16)(oacc[dt][1] * rl));
    hs.z = h2u((f16)(oacc[dt][2] * rl)); hs.w = h2u((f16)(oacc[dt][3] * rl));
    *(ushort4*)(oq + obase + dt * 16 + kg * 4) = hs;
  }
}

// ---------------- driver -----------------------------------------------------
extern "C" void kernel_launch(void* const* d_in, const int* in_sizes, int n_in,
                              void* d_out, int out_size, void* d_ws, size_t ws_size,
                              hipStream_t stream)
{
  const float* patches   = (const float*)d_in[0];
  const int*   h_idx     = (const int*)d_in[1];
  const int*   w_idx     = (const int*)d_in[2];
  const int*   image_ids = (const int*)d_in[3];
  const float* pos_h = (const float*)d_in[4];
  const float* pos_w = (const float*)d_in[5];
  const float* Wp  = (const float*)d_in[6];
  const float* bp  = (const float*)d_in[7];
  const float* lnp = (const float*)d_in[8];
  const float* ln1 = (const float*)d_in[9];
  const float* qg  = (const float*)d_in[10];
  const float* kg  = (const float*)d_in[11];
  const float* Wq  = (const float*)d_in[12];
  const float* Wkv = (const float*)d_in[13];
  const float* Wo  = (const float*)d_in[14];
  const float* ln2 = (const float*)d_in[15];
  const float* W1  = (const float*)d_in[16];
  const float* b1  = (const float*)d_in[17];
  const float* W2  = (const float*)d_in[18];
  const float* b2  = (const float*)d_in[19];
  const float* lnf = (const float*)d_in[20];
  float* out = (float*)d_out;

  char* w = (char*)d_ws;
  float* x = (float*)w;            w += (size_t)NTOK * DIM * 4;
  f16* pbufh = (f16*)w;            w += (size_t)4 * NTOK * DIM * 2;   // split-K partials / Wp weights
  f16* qh  = (f16*)w;              w += (size_t)NTOK * DIM * 2;
  f16* ktb = (f16*)w;              w += (size_t)NTOK * DIM * 2;
  f16* vtb = (f16*)w;              w += (size_t)NTOK * DIM * 2;
  f16* aAq = (f16*)w;              w += (size_t)NTOK * DIM * 2;
  f16* aBq = (f16*)w;              w += (size_t)NTOK * MLP_ * 2;      // also f32 tmp
  int2* segs = (int2*)w;           w += (size_t)NTOK * 8;
  f16* wlA = (f16*)w;              w += (size_t)WELTS * 2;            // alternating hot
  f16* wlB = (f16*)w;                                                  // weight buffers
  float* ptmp = (float*)aBq;       // 2048*768 f32 fits in aBq region
  f16* wpc = pbufh;                // Wp converted (1.2MB) — dead until first W2

  seg_kernel<<<dim3(4, 2), 256, 0, stream>>>(image_ids, segs);
  posadd_kernel<<<1536, 256, 0, stream>>>(patches, h_idx, w_idx, pos_h, pos_w, aAq);
  convert_w_kernel<<<144, 256, 0, stream>>>(Wp, nullptr, nullptr, nullptr, nullptr, 0, 1, wpc);
  gemm_small<<<384, 256, 0, stream>>>(aAq, wpc, bp, nullptr, ptmp, DIM, DIM, 12);
  lnred_kernel<<<NTOK / 4, 256, 0, stream>>>(ptmp, nullptr, nullptr, 0, lnp, nullptr, x);
  convert_w_kernel<<<1728, 256, 0, stream>>>(Wq, Wkv, Wo, W1, W2, 0, 0, wlA);

  for (int i = 0; i < 8; i++){
    f16* wcur = (i & 1) ? wlB : wlA;
    f16* wnxt = (i & 1) ? wlA : wlB;
    // fused: x += (prev-layer W2 partials + b2) ; ln1 -> aAq (f16)
    lnred_kernel<<<NTOK / 4, 256, 0, stream>>>(
        x, pbufh, i ? (b2 + (i - 1) * DIM) : nullptr, i ? 4 : 0,
        ln1 + i * DIM, aAq, nullptr);
    // merged: qkv projection (+fused rmsnorm) || next-layer weight convert
    qkvconv_kernel<<<2016, 256, 0, stream>>>(
        aAq, wcur, qh, ktb, vtb, qg + i * DIM, kg + i * DIM,
        Wq, Wkv, Wo, W1, W2, (i < 7) ? i + 1 : -1, wnxt);
    attn_kernel<<<dim3(24, 16), 256, 0, stream>>>(qh, ktb, vtb, segs, aAq);
    gemm_small<<<384, 256, 0, stream>>>(
        aAq, wcur + 1769472, nullptr, x, x, DIM, DIM, 12);
    lnred_kernel<<<NTOK / 4, 256, 0, stream>>>(
        x, nullptr, nullptr, 0, ln2 + i * DIM, aAq, nullptr);
    gemm_big<<<384, 256, 0, stream>>>(
        aAq, wcur + 2359296, b1 + i * MLP_, aBq, nullptr, nullptr, nullptr,
        nullptr, nullptr, MLP_, DIM, 24, 1);
    gemm_big<<<dim3(96, 1, 4), 256, 0, stream>>>(
        aBq, wcur + 4718592, nullptr, pbufh, nullptr, nullptr, nullptr,
        nullptr, nullptr, DIM, MLP_, 6, 3);
  }
  lnred_kernel<<<NTOK / 4, 256, 0, stream>>>(x, pbufh, b2 + 7 * DIM, 4, lnf, nullptr, out);
}

// Round 15
// 908.515 us; speedup vs baseline: 1.3701x; 1.3701x over previous
//
#include <hip/hip_runtime.h>
#include <hip/hip_bf16.h>
#include <math.h>

typedef _Float16 f16;
typedef f16   f16x8 __attribute__((ext_vector_type(8)));
typedef float f32x4 __attribute__((ext_vector_type(4)));
typedef unsigned short ushort_t;

#define DIM   768
#define HEADS 12
#define DH    64
#define MLP_  3072
#define NTOK  2048
#define SEQ   1024
#define WELTS 7077888   // per-layer converted weight elements (Wq+Wkv+Wo+W1+W2)

__device__ __forceinline__ ushort_t h2u(f16 h){ return __builtin_bit_cast(ushort_t, h); }
__device__ __forceinline__ unsigned pk2h(float a, float b){
  return (unsigned)h2u((f16)a) | ((unsigned)h2u((f16)b) << 16);
}
__device__ __forceinline__ void gload16(const void* g, void* l){
  __builtin_amdgcn_global_load_lds(
      (const __attribute__((address_space(1))) void*)g,
      (__attribute__((address_space(3))) void*)l, 16, 0, 0);
}
__device__ __forceinline__ float wred_sum(float v){
  #pragma unroll
  for (int o = 32; o > 0; o >>= 1) v += __shfl_xor(v, o);
  return v;
}

// ---------- weight convert body: W[K][N] f32 -> Wt [N][K] f16 ----------------
__device__ __forceinline__ void convert_body(
    int bid, const float* __restrict__ Wq, const float* __restrict__ Wkv,
    const float* __restrict__ Wo, const float* __restrict__ W1,
    const float* __restrict__ W2, int layer, int wp_only,
    f16* __restrict__ th)
{
  const float* src; int K, N; size_t ooff; int t;
  if (wp_only){ src = Wq; K = 768; N = 768; ooff = 0; t = bid; }
  else if (bid < 144) { src = Wq;  K = 768;  N = 768;  ooff = 0;       t = bid; }
  else if (bid < 432) { src = Wkv; K = 768;  N = 1536; ooff = 589824;  t = bid - 144; }
  else if (bid < 576) { src = Wo;  K = 768;  N = 768;  ooff = 1769472; t = bid - 432; }
  else if (bid < 1152){ src = W1;  K = 768;  N = 3072; ooff = 2359296; t = bid - 576; }
  else                { src = W2;  K = 3072; N = 768;  ooff = 4718592; t = bid - 1152; }
  if (!wp_only) src += (size_t)layer * K * N;
  int ntn = N >> 6;
  int tk = t / ntn, tn = t % ntn;
  int k0 = tk * 64, n0 = tn * 64;

  __shared__ unsigned lp[32][66];
  const int tid = threadIdx.x;
  #pragma unroll
  for (int p = 0; p < 2; p++){
    int rp = p * 16 + (tid >> 4);
    int c  = (tid & 15) * 4;
    const float* s0 = src + (size_t)(k0 + 2 * rp) * N + n0 + c;
    float4 a = *(const float4*)s0;
    float4 b = *(const float4*)(s0 + N);
    unsigned u0 = pk2h(a.x, b.x), u1 = pk2h(a.y, b.y);
    unsigned u2 = pk2h(a.z, b.z), u3 = pk2h(a.w, b.w);
    *(uint4*)&lp[rp][c] = make_uint4(u0, u1, u2, u3);
  }
  __syncthreads();
  #pragma unroll
  for (int p = 0; p < 2; p++){
    int n = p * 32 + (tid >> 3);
    int q = tid & 7;
    unsigned u[4];
    #pragma unroll
    for (int j = 0; j < 4; j++) u[j] = lp[q * 4 + j][n];
    *(uint4*)(th + ooff + (size_t)(n0 + n) * K + k0 + q * 8)
        = make_uint4(u[0], u[1], u[2], u[3]);
  }
}

__global__ __launch_bounds__(256) void convert_w_kernel(
    const float* __restrict__ Wq, const float* __restrict__ Wkv,
    const float* __restrict__ Wo, const float* __restrict__ W1,
    const float* __restrict__ W2, int layer, int wp_only,
    f16* __restrict__ th)
{
  convert_body(blockIdx.x, Wq, Wkv, Wo, W1, W2, layer, wp_only, th);
}

// ------------- big GEMM body: 128x128 block, 4 waves of 64x64, BK=64 ---------
// single-buffer LDS (32KB), XOR-swizzled via pre-swizzled global_load_lds src.
// mode 1: f16 gelu(acc+bias) -> Cq[N]
// mode 2: qkv epilogue (fused qk-rmsnorm, gammas folded into Q)
// mode 3: split-K f16 partial -> Cq + z*NTOK*N
__device__ __forceinline__ void gemm_big_body(
    int bid, int bz, int nz,
    const f16* __restrict__ Aq, const f16* __restrict__ Bw,
    const float* __restrict__ bias,
    f16* __restrict__ Cq,
    f16* __restrict__ Qh, f16* __restrict__ Kt, f16* __restrict__ Vt,
    const float* __restrict__ qgam, const float* __restrict__ kgam,
    int N, int K, int nbx, int mode)
{
  __shared__ __align__(16) f16 sA[128 * 64];
  __shared__ __align__(16) f16 sB[128 * 64];
  const int tid = threadIdx.x;
  const int wid = tid >> 6, lane = tid & 63;
  const int nwg = nbx << 4;
  const int swz = (bid & 7) * (nwg >> 3) + (bid >> 3);
  const int by = swz & 15, bx = swz >> 4;
  const int brow = by << 7, bcol = bx << 7;
  const int m2 = wid & 1, n2 = wid >> 1;
  const int fr = lane & 15, fq = lane >> 4;
  const int Kc = K / nz;
  const int kbase = bz * Kc;
  const int nk = Kc >> 6;

  const f16* pA = Aq + (size_t)brow * K + kbase;
  const f16* pB = Bw + (size_t)bcol * K + kbase;

  f32x4 acc[4][4] = {};

  for (int ks = 0; ks < nk; ks++){
    const int k0 = ks << 6;
    if (ks) __syncthreads();
    #pragma unroll
    for (int i = 0; i < 4; i++){
      int idx = tid + i * 256;
      int r = idx >> 3, c = idx & 7;
      int gc = c ^ (r & 7);
      gload16(pA + (size_t)r * K + k0 + gc * 8, &sA[idx * 8]);
      gload16(pB + (size_t)r * K + k0 + gc * 8, &sB[idx * 8]);
    }
    __syncthreads();
    #pragma unroll
    for (int s = 0; s < 2; s++){
      f16x8 a[4], b[4];
      #pragma unroll
      for (int m = 0; m < 4; m++){
        int r = m2 * 64 + m * 16 + fr;
        int ch = (s * 4 + fq) ^ (r & 7);
        a[m] = *(const f16x8*)(&sA[r * 64 + ch * 8]);
      }
      #pragma unroll
      for (int n = 0; n < 4; n++){
        int r = n2 * 64 + n * 16 + fr;
        int ch = (s * 4 + fq) ^ (r & 7);
        b[n] = *(const f16x8*)(&sB[r * 64 + ch * 8]);
      }
      #pragma unroll
      for (int m = 0; m < 4; m++)
        #pragma unroll
        for (int n = 0; n < 4; n++)
          acc[m][n] = __builtin_amdgcn_mfma_f32_16x16x32_f16(a[m], b[n], acc[m][n], 0, 0, 0);
    }
  }

  // epilogue: D layout col=lane&15, row=(lane>>4)*4+i
  if (mode == 2){
    const int hbase = bcol + n2 * 64;   // wave-uniform, 64-aligned head block
    if (hbase < 768){
      float gp[4];
      #pragma unroll
      for (int n = 0; n < 4; n++){
        int col = hbase + n * 16 + fr;
        gp[n] = qgam[col] * kgam[col];
      }
      #pragma unroll
      for (int m = 0; m < 4; m++)
        #pragma unroll
        for (int i = 0; i < 4; i++){
          float s = 0.f;
          #pragma unroll
          for (int n = 0; n < 4; n++) s += acc[m][n][i] * acc[m][n][i];
          s += __shfl_xor(s, 1); s += __shfl_xor(s, 2);
          s += __shfl_xor(s, 4); s += __shfl_xor(s, 8);
          float f = 8.f / fmaxf(sqrtf(s), 1e-12f);
          int row = brow + m2 * 64 + m * 16 + (fq << 2) + i;
          #pragma unroll
          for (int n = 0; n < 4; n++)
            Qh[(size_t)row * 768 + hbase + n * 16 + fr] = (f16)(acc[m][n][i] * f * gp[n]);
        }
    } else if (hbase < 1536){
      int hh = (hbase - 768) >> 6;
      #pragma unroll
      for (int m = 0; m < 4; m++)
        #pragma unroll
        for (int i = 0; i < 4; i++){
          float s = 0.f;
          #pragma unroll
          for (int n = 0; n < 4; n++) s += acc[m][n][i] * acc[m][n][i];
          s += __shfl_xor(s, 1); s += __shfl_xor(s, 2);
          s += __shfl_xor(s, 4); s += __shfl_xor(s, 8);
          float f = 8.f / fmaxf(sqrtf(s), 1e-12f);
          int row = brow + m2 * 64 + m * 16 + (fq << 2) + i;
          int bq = row >> 10, tok = row & 1023;
          #pragma unroll
          for (int n = 0; n < 4; n++)
            Kt[((size_t)(bq * 12 + hh) * 1024 + tok) * 64 + n * 16 + fr]
                = (f16)(acc[m][n][i] * f);
        }
    } else {
      int hh = (hbase - 1536) >> 6;
      #pragma unroll
      for (int n = 0; n < 4; n++){
        int dd = n * 16 + fr;
        #pragma unroll
        for (int m = 0; m < 4; m++){
          int row0 = brow + m2 * 64 + m * 16 + (fq << 2);
          int bq = row0 >> 10, tok0 = row0 & 1023;
          ushort4 sv;
          sv.x = h2u((f16)acc[m][n][0]); sv.y = h2u((f16)acc[m][n][1]);
          sv.z = h2u((f16)acc[m][n][2]); sv.w = h2u((f16)acc[m][n][3]);
          *(ushort4*)(Vt + ((size_t)((bq * 12 + hh) * 64 + dd)) * 1024 + tok0) = sv;
        }
      }
    }
  } else if (mode == 1){
    #pragma unroll
    for (int n = 0; n < 4; n++){
      int col = bcol + n2 * 64 + n * 16 + fr;
      float bv = bias[col];
      #pragma unroll
      for (int m = 0; m < 4; m++){
        int row0 = brow + m2 * 64 + m * 16 + (fq << 2);
        #pragma unroll
        for (int i = 0; i < 4; i++){
          float v = acc[m][n][i] + bv;
          float ge = 0.5f * v * (1.f + erff(v * 0.70710678118654752f));
          Cq[(size_t)(row0 + i) * N + col] = (f16)ge;
        }
      }
    }
  } else {  // mode 3: f16 split-K partials
    f16* P = Cq + (size_t)bz * ((size_t)NTOK * N);
    #pragma unroll
    for (int n = 0; n < 4; n++){
      int col = bcol + n2 * 64 + n * 16 + fr;
      #pragma unroll
      for (int m = 0; m < 4; m++){
        int row0 = brow + m2 * 64 + m * 16 + (fq << 2);
        #pragma unroll
        for (int i = 0; i < 4; i++)
          P[(size_t)(row0 + i) * N + col] = (f16)acc[m][n][i];
      }
    }
  }
}

__global__ __launch_bounds__(256) void gemm_big(
    const f16* __restrict__ Aq, const f16* __restrict__ Bw,
    const float* __restrict__ bias,
    f16* __restrict__ Cq,
    f16* __restrict__ Qh, f16* __restrict__ Kt, f16* __restrict__ Vt,
    const float* __restrict__ qgam, const float* __restrict__ kgam,
    int N, int K, int nbx, int mode)
{
  gemm_big_body(blockIdx.x, blockIdx.z, (int)gridDim.z,
                Aq, Bw, bias, Cq, Qh, Kt, Vt, qgam, kgam, N, K, nbx, mode);
}

// ------ merged: qkv projection (blocks 0-287) + next-layer convert (288+) ----
__global__ __launch_bounds__(256) void qkvconv_kernel(
    const f16* __restrict__ Aq, const f16* __restrict__ Bw,
    f16* __restrict__ Qh, f16* __restrict__ Kt, f16* __restrict__ Vt,
    const float* __restrict__ qgam, const float* __restrict__ kgam,
    const float* __restrict__ Wq, const float* __restrict__ Wkv,
    const float* __restrict__ Wo, const float* __restrict__ W1,
    const float* __restrict__ W2, int nlayer, f16* __restrict__ thn)
{
  if (blockIdx.x < 288)
    gemm_big_body((int)blockIdx.x, 0, 1, Aq, Bw, nullptr, nullptr,
                  Qh, Kt, Vt, qgam, kgam, 3 * DIM, DIM, 18, 2);
  else if (nlayer >= 0)
    convert_body((int)blockIdx.x - 288, Wq, Wkv, Wo, W1, W2, nlayer, 0, thn);
}

// ------------- small GEMM (64x64 block, 4 waves of 32x32): f32 out -----------
__global__ __launch_bounds__(256) void gemm_small(
    const f16* __restrict__ Aq, const f16* __restrict__ Bw,
    const float* __restrict__ bias, const float* __restrict__ res,
    float* __restrict__ C, int N, int K, int nbx)
{
  __shared__ __align__(16) f16 sA[2][64 * 64];
  __shared__ __align__(16) f16 sB[2][64 * 64];
  const int tid = threadIdx.x;
  const int wid = tid >> 6, lane = tid & 63;
  const int nwg = nbx << 5;
  const int bid = blockIdx.x;
  const int swz = (bid & 7) * (nwg >> 3) + (bid >> 3);
  const int by = swz & 31, bx = swz >> 5;
  const int brow = by << 6, bcol = bx << 6;
  const int m2 = wid & 1, n2 = wid >> 1;
  const int fr = lane & 15, fq = lane >> 4;
  const int nk = K >> 6;

  const f16* pA = Aq + (size_t)brow * K;
  const f16* pB = Bw + (size_t)bcol * K;

  f32x4 acc[2][2] = {};

  auto STAGE = [&](int buf, int ks){
    const int k0 = ks << 6;
    #pragma unroll
    for (int i = 0; i < 2; i++){
      int idx = tid + i * 256;
      int r = idx >> 3, c = idx & 7;
      int gc = c ^ (r & 7);
      gload16(pA + (size_t)r * K + k0 + gc * 8, &sA[buf][idx * 8]);
      gload16(pB + (size_t)r * K + k0 + gc * 8, &sB[buf][idx * 8]);
    }
  };

  STAGE(0, 0);
  __syncthreads();
  int cur = 0;
  for (int ks = 0; ks < nk; ks++){
    if (ks + 1 < nk) STAGE(cur ^ 1, ks + 1);
    #pragma unroll
    for (int s = 0; s < 2; s++){
      f16x8 a[2], b[2];
      #pragma unroll
      for (int m = 0; m < 2; m++){
        int r = m2 * 32 + m * 16 + fr;
        int ch = (s * 4 + fq) ^ (r & 7);
        a[m] = *(const f16x8*)(&sA[cur][r * 64 + ch * 8]);
      }
      #pragma unroll
      for (int n = 0; n < 2; n++){
        int r = n2 * 32 + n * 16 + fr;
        int ch = (s * 4 + fq) ^ (r & 7);
        b[n] = *(const f16x8*)(&sB[cur][r * 64 + ch * 8]);
      }
      #pragma unroll
      for (int m = 0; m < 2; m++)
        #pragma unroll
        for (int n = 0; n < 2; n++)
          acc[m][n] = __builtin_amdgcn_mfma_f32_16x16x32_f16(a[m], b[n], acc[m][n], 0, 0, 0);
    }
    __syncthreads();
    cur ^= 1;
  }

  #pragma unroll
  for (int n = 0; n < 2; n++){
    int col = bcol + n2 * 32 + n * 16 + fr;
    float bv = bias ? bias[col] : 0.f;
    #pragma unroll
    for (int m = 0; m < 2; m++){
      int row0 = brow + m2 * 32 + m * 16 + (fq << 2);
      #pragma unroll
      for (int i = 0; i < 4; i++){
        float v = acc[m][n][i] + bv;
        size_t o = (size_t)(row0 + i) * N + col;
        if (res) v += res[o];
        C[o] = v;
      }
    }
  }
}

// ------- fused (optional 4-way f16 split-K reduce + badd + residual) + LN ----
__global__ __launch_bounds__(256) void lnred_kernel(
    float* __restrict__ x, const f16* __restrict__ p, const float* __restrict__ badd,
    int npart, const float* __restrict__ g, f16* __restrict__ yq, float* __restrict__ yf)
{
  int wid = threadIdx.x >> 6, lane = threadIdx.x & 63;
  int row = blockIdx.x * 4 + wid;
  float* xr = x + (size_t)row * DIM;
  float v[12]; float s = 0.f;
  if (npart){
    #pragma unroll
    for (int d = 0; d < 12; d++){
      int c = d * 64 + lane;
      float t = xr[c] + badd[c];
      #pragma unroll
      for (int j = 0; j < 4; j++)
        t += (float)p[(size_t)j * (NTOK * DIM) + (size_t)row * DIM + c];
      xr[c] = t; v[d] = t; s += t;
    }
  } else {
    #pragma unroll
    for (int d = 0; d < 12; d++){ v[d] = xr[d * 64 + lane]; s += v[d]; }
  }
  s = wred_sum(s);
  float mean = s * (1.f / 768.f);
  float q2 = 0.f;
  #pragma unroll
  for (int d = 0; d < 12; d++){ float t = v[d] - mean; q2 += t * t; }
  q2 = wred_sum(q2);
  float rstd = rsqrtf(q2 * (1.f / 768.f) + 1e-5f);
  size_t base = (size_t)row * DIM;
  #pragma unroll
  for (int d = 0; d < 12; d++){
    float y = (v[d] - mean) * rstd * g[d * 64 + lane];
    if (yq) yq[base + d * 64 + lane] = (f16)y;
    else    yf[base + d * 64 + lane] = y;
  }
}

// ---------------- pos-embed add -> f16 ---------------------------------------
__global__ __launch_bounds__(256) void posadd_kernel(
    const float* __restrict__ patches, const int* __restrict__ hi,
    const int* __restrict__ wi, const float* __restrict__ ph,
    const float* __restrict__ pw, f16* __restrict__ oq)
{
  int idx = blockIdx.x * 256 + threadIdx.x;
  int tok = idx / 192, cv = idx % 192;
  float4 p = ((const float4*)patches)[idx];
  float4 a = *(const float4*)(ph + (size_t)hi[tok] * DIM + cv * 4);
  float4 b = *(const float4*)(pw + (size_t)wi[tok] * DIM + cv * 4);
  ushort4 o;
  o.x = h2u((f16)(p.x + a.x + b.x)); o.y = h2u((f16)(p.y + a.y + b.y));
  o.z = h2u((f16)(p.z + a.z + b.z)); o.w = h2u((f16)(p.w + a.w + b.w));
  ((ushort4*)oq)[idx] = o;
}

// ---------------- segment ranges from sorted image_ids -----------------------
__global__ void seg_kernel(const int* __restrict__ ids, int2* __restrict__ segs)
{
  int i = blockIdx.x * 256 + threadIdx.x;
  int b = blockIdx.y;
  const int* row = ids + b * SEQ;
  int v = row[i];
  int lo = 0, hi = SEQ;
  while (lo < hi){ int mid = (lo + hi) >> 1; if (row[mid] <  v) lo = mid + 1; else hi = mid; }
  int s = lo;
  lo = 0; hi = SEQ;
  while (lo < hi){ int mid = (lo + hi) >> 1; if (row[mid] <= v) lo = mid + 1; else hi = mid; }
  segs[b * SEQ + i] = make_int2(s, lo);
}

// --------- MFMA flash attention over segments (all-f16, KVBLK=64) ------------
// grid = (qt, bh): consecutive blocks share one (b,h) K/V panel -> L2 locality.
__global__ __launch_bounds__(256) void attn_kernel(
    const f16* __restrict__ qh, const f16* __restrict__ ktp,
    const f16* __restrict__ vt, const int2* __restrict__ segs,
    f16* __restrict__ oq)
{
  __shared__ __align__(16) ushort_t Kq[64 * 64];    // 8 KB, XOR-swizzled rows
  __shared__ __align__(16) ushort_t Vl[64 * 72];    // 9 KB, [d][key] stride 144B

  const int tid = threadIdx.x;
  const int w = tid >> 6, lane = tid & 63;
  const int q15 = lane & 15, kg = lane >> 4;
  const int bh = blockIdx.y, b = bh / 12, h = bh % 12;
  const int qt = blockIdx.x;
  const int qrow = qt * 64 + w * 16 + q15;
  const size_t qtok = (size_t)b * SEQ + qrow;

  const f16* qp = qh + qtok * DIM + h * 64 + kg * 8;
  f16x8 qf[2];
  qf[0] = *(const f16x8*)(qp);
  qf[1] = *(const f16x8*)(qp + 32);

  const int2 se  = segs[qtok];
  const int2 se0 = segs[(size_t)b * SEQ + qt * 64];
  const int2 se1 = segs[(size_t)b * SEQ + qt * 64 + 63];
  const int klo = se0.x & ~63, khi = se1.y;

  float m = -3.0e38f, l = 0.f;
  f32x4 oacc[4] = {};

  const f16* kbase = ktp + (size_t)bh * 1024 * 64;
  const int vd = tid >> 2, vc0 = tid & 3;

  for (int kt0 = klo; kt0 < khi; kt0 += 64){
    #pragma unroll
    for (int i = 0; i < 2; i++){
      int idx = tid + i * 256;
      int r = idx >> 3, c = idx & 7;
      int gc = c ^ (r & 7);
      gload16(kbase + (size_t)(kt0 + r) * 64 + gc * 8, Kq + idx * 8);
    }
    #pragma unroll
    for (int p2 = 0; p2 < 2; p2++){
      int chunk = vc0 + p2 * 4;
      uint4 vv = *(const uint4*)(vt + ((size_t)bh * 64 + vd) * SEQ + kt0 + chunk * 8);
      *(uint4*)((char*)Vl + vd * 144 + chunk * 16) = vv;
    }
    __syncthreads();

    f32x4 s[4] = {};
    #pragma unroll
    for (int dh2 = 0; dh2 < 2; dh2++){
      #pragma unroll
      for (int khf = 0; khf < 4; khf++){
        int row = khf * 16 + q15;
        unsigned off = ((unsigned)row << 7) + ((unsigned)(dh2 * 4 + kg) << 4);
        off ^= (unsigned)(row & 7) << 4;
        f16x8 kf = *(const f16x8*)((const char*)Kq + off);
        s[khf] = __builtin_amdgcn_mfma_f32_16x16x32_f16(kf, qf[dh2], s[khf], 0, 0, 0);
      }
    }

    float p[16]; float tmax = -3.0e38f;
    #pragma unroll
    for (int khf = 0; khf < 4; khf++)
      #pragma unroll
      for (int i = 0; i < 4; i++){
        int key = kt0 + khf * 16 + kg * 4 + i;
        bool val = (key >= se.x) && (key < se.y);
        float sv = val ? s[khf][i] : -3.0e38f;
        p[khf * 4 + i] = sv;
        tmax = fmaxf(tmax, sv);
      }
    tmax = fmaxf(tmax, __shfl_xor(tmax, 16));
    tmax = fmaxf(tmax, __shfl_xor(tmax, 32));
    float mnew = fmaxf(m, tmax);
    float sc = __expf(m - mnew);
    float psum = 0.f;
    #pragma unroll
    for (int j = 0; j < 16; j++){
      float pv = (p[j] > -1.0e38f) ? __expf(p[j] - mnew) : 0.f;
      p[j] = pv; psum += pv;
    }
    psum += __shfl_xor(psum, 16);
    psum += __shfl_xor(psum, 32);
    l = l * sc + psum;
    m = mnew;
    #pragma unroll
    for (int dt = 0; dt < 4; dt++) oacc[dt] *= sc;

    int s0l = q15 + ((kg & 1) << 5);
    int s1l = s0l + 16;
    bool hih = kg >= 2;
    unsigned uA0 = pk2h(p[0],  p[1]),  uA1 = pk2h(p[2],  p[3]);
    unsigned uA2 = pk2h(p[4],  p[5]),  uA3 = pk2h(p[6],  p[7]);
    unsigned uB0 = pk2h(p[8],  p[9]),  uB1 = pk2h(p[10], p[11]);
    unsigned uB2 = pk2h(p[12], p[13]), uB3 = pk2h(p[14], p[15]);
    unsigned a0 = __shfl(uA0, s0l), b0 = __shfl(uA1, s0l);
    unsigned a1 = __shfl(uA0, s1l), b1 = __shfl(uA1, s1l);
    unsigned c0 = __shfl(uA2, s0l), d0 = __shfl(uA3, s0l);
    unsigned c1 = __shfl(uA2, s1l), d1 = __shfl(uA3, s1l);
    f16x8 pfA = __builtin_bit_cast(f16x8,
        make_uint4(hih ? c0 : a0, hih ? d0 : b0, hih ? c1 : a1, hih ? d1 : b1));
    unsigned e0 = __shfl(uB0, s0l), f0 = __shfl(uB1, s0l);
    unsigned e1 = __shfl(uB0, s1l), f1 = __shfl(uB1, s1l);
    unsigned g0 = __shfl(uB2, s0l), h0 = __shfl(uB3, s0l);
    unsigned g1 = __shfl(uB2, s1l), h1 = __shfl(uB3, s1l);
    f16x8 pfB = __builtin_bit_cast(f16x8,
        make_uint4(hih ? g0 : e0, hih ? h0 : f0, hih ? g1 : e1, hih ? h1 : f1));

    #pragma unroll
    for (int dt = 0; dt < 4; dt++){
      const char* vb = (const char*)Vl + (dt * 16 + q15) * 144 + kg * 16;
      f16x8 vfA = *(const f16x8*)vb;
      f16x8 vfB = *(const f16x8*)(vb + 64);
      oacc[dt] = __builtin_amdgcn_mfma_f32_16x16x32_f16(vfA, pfA, oacc[dt], 0, 0, 0);
      oacc[dt] = __builtin_amdgcn_mfma_f32_16x16x32_f16(vfB, pfB, oacc[dt], 0, 0, 0);
    }
    __syncthreads();
  }

  float rl = 1.f / l;
  size_t obase = qtok * DIM + h * 64;
  #pragma unroll
  for (int dt = 0; dt < 4; dt++){
    ushort4 hs;
    hs.x = h2u((f16)(oacc[dt][0] * rl)); hs.y = h2u((f16)(oacc[dt][1] * rl));
    hs.z = h2u((f16)(oacc[dt][2] * rl)); hs.w = h2u((f16)(oacc[dt][3] * rl));
    *(ushort4*)(oq + obase + dt * 16 + kg * 4) = hs;
  }
}

// ---------------- driver -----------------------------------------------------
extern "C" void kernel_launch(void* const* d_in, const int* in_sizes, int n_in,
                              void* d_out, int out_size, void* d_ws, size_t ws_size,
                              hipStream_t stream)
{
  const float* patches   = (const float*)d_in[0];
  const int*   h_idx     = (const int*)d_in[1];
  const int*   w_idx     = (const int*)d_in[2];
  const int*   image_ids = (const int*)d_in[3];
  const float* pos_h = (const float*)d_in[4];
  const float* pos_w = (const float*)d_in[5];
  const float* Wp  = (const float*)d_in[6];
  const float* bp  = (const float*)d_in[7];
  const float* lnp = (const float*)d_in[8];
  const float* ln1 = (const float*)d_in[9];
  const float* qg  = (const float*)d_in[10];
  const float* kg  = (const float*)d_in[11];
  const float* Wq  = (const float*)d_in[12];
  const float* Wkv = (const float*)d_in[13];
  const float* Wo  = (const float*)d_in[14];
  const float* ln2 = (const float*)d_in[15];
  const float* W1  = (const float*)d_in[16];
  const float* b1  = (const float*)d_in[17];
  const float* W2  = (const float*)d_in[18];
  const float* b2  = (const float*)d_in[19];
  const float* lnf = (const float*)d_in[20];
  float* out = (float*)d_out;

  char* w = (char*)d_ws;
  float* x = (float*)w;            w += (size_t)NTOK * DIM * 4;
  f16* pbufh = (f16*)w;            w += (size_t)4 * NTOK * DIM * 2;   // split-K partials / Wp weights
  f16* qh  = (f16*)w;              w += (size_t)NTOK * DIM * 2;
  f16* ktb = (f16*)w;              w += (size_t)NTOK * DIM * 2;
  f16* vtb = (f16*)w;              w += (size_t)NTOK * DIM * 2;
  f16* aAq = (f16*)w;              w += (size_t)NTOK * DIM * 2;
  f16* aBq = (f16*)w;              w += (size_t)NTOK * MLP_ * 2;      // also f32 tmp
  int2* segs = (int2*)w;           w += (size_t)NTOK * 8;
  f16* wlA = (f16*)w;              w += (size_t)WELTS * 2;            // alternating hot
  f16* wlB = (f16*)w;                                                  // weight buffers
  float* ptmp = (float*)aBq;       // 2048*768 f32 fits in aBq region
  f16* wpc = pbufh;                // Wp converted (1.2MB) — dead until first W2

  seg_kernel<<<dim3(4, 2), 256, 0, stream>>>(image_ids, segs);
  posadd_kernel<<<1536, 256, 0, stream>>>(patches, h_idx, w_idx, pos_h, pos_w, aAq);
  convert_w_kernel<<<144, 256, 0, stream>>>(Wp, nullptr, nullptr, nullptr, nullptr, 0, 1, wpc);
  gemm_small<<<384, 256, 0, stream>>>(aAq, wpc, bp, nullptr, ptmp, DIM, DIM, 12);
  lnred_kernel<<<NTOK / 4, 256, 0, stream>>>(ptmp, nullptr, nullptr, 0, lnp, nullptr, x);
  convert_w_kernel<<<1728, 256, 0, stream>>>(Wq, Wkv, Wo, W1, W2, 0, 0, wlA);

  for (int i = 0; i < 8; i++){
    f16* wcur = (i & 1) ? wlB : wlA;
    f16* wnxt = (i & 1) ? wlA : wlB;
    // fused: x += (prev-layer W2 partials + b2) ; ln1 -> aAq (f16)
    lnred_kernel<<<NTOK / 4, 256, 0, stream>>>(
        x, pbufh, i ? (b2 + (i - 1) * DIM) : nullptr, i ? 4 : 0,
        ln1 + i * DIM, aAq, nullptr);
    // merged: qkv projection (+fused rmsnorm) || next-layer weight convert
    qkvconv_kernel<<<2016, 256, 0, stream>>>(
        aAq, wcur, qh, ktb, vtb, qg + i * DIM, kg + i * DIM,
        Wq, Wkv, Wo, W1, W2, (i < 7) ? i + 1 : -1, wnxt);
    attn_kernel<<<dim3(16, 24), 256, 0, stream>>>(qh, ktb, vtb, segs, aAq);
    gemm_small<<<384, 256, 0, stream>>>(
        aAq, wcur + 1769472, nullptr, x, x, DIM, DIM, 12);
    lnred_kernel<<<NTOK / 4, 256, 0, stream>>>(
        x, nullptr, nullptr, 0, ln2 + i * DIM, aAq, nullptr);
    gemm_big<<<384, 256, 0, stream>>>(
        aAq, wcur + 2359296, b1 + i * MLP_, aBq, nullptr, nullptr, nullptr,
        nullptr, nullptr, MLP_, DIM, 24, 1);
    gemm_big<<<dim3(96, 1, 4), 256, 0, stream>>>(
        aBq, wcur + 4718592, nullptr, pbufh, nullptr, nullptr, nullptr,
        nullptr, nullptr, DIM, MLP_, 6, 3);
  }
  lnred_kernel<<<NTOK / 4, 256, 0, stream>>>(x, pbufh, b2 + 7 * DIM, 4, lnf, nullptr, out);
}

// Round 16
// 881.715 us; speedup vs baseline: 1.4117x; 1.0304x over previous
//
#include <hip/hip_runtime.h>
#include <hip/hip_bf16.h>
#include <math.h>

typedef _Float16 f16;
typedef f16   f16x8 __attribute__((ext_vector_type(8)));
typedef float f32x4 __attribute__((ext_vector_type(4)));
typedef unsigned short ushort_t;

#define DIM   768
#define HEADS 12
#define DH    64
#define MLP_  3072
#define NTOK  2048
#define SEQ   1024
#define WELTS 7077888   // per-layer converted weight elements (Wq+Wkv+Wo+W1+W2)

__device__ __forceinline__ ushort_t h2u(f16 h){ return __builtin_bit_cast(ushort_t, h); }
__device__ __forceinline__ unsigned pk2h(float a, float b){
  return (unsigned)h2u((f16)a) | ((unsigned)h2u((f16)b) << 16);
}
__device__ __forceinline__ void gload16(const void* g, void* l){
  __builtin_amdgcn_global_load_lds(
      (const __attribute__((address_space(1))) void*)g,
      (__attribute__((address_space(3))) void*)l, 16, 0, 0);
}
__device__ __forceinline__ float wred_sum(float v){
  #pragma unroll
  for (int o = 32; o > 0; o >>= 1) v += __shfl_xor(v, o);
  return v;
}

// ---------- weight convert body: W[K][N] f32 -> Wt [N][K] f16 ----------------
__device__ __forceinline__ void convert_body(
    int bid, const float* __restrict__ Wq, const float* __restrict__ Wkv,
    const float* __restrict__ Wo, const float* __restrict__ W1,
    const float* __restrict__ W2, int layer, int wp_only,
    f16* __restrict__ th)
{
  const float* src; int K, N; size_t ooff; int t;
  if (wp_only){ src = Wq; K = 768; N = 768; ooff = 0; t = bid; }
  else if (bid < 144) { src = Wq;  K = 768;  N = 768;  ooff = 0;       t = bid; }
  else if (bid < 432) { src = Wkv; K = 768;  N = 1536; ooff = 589824;  t = bid - 144; }
  else if (bid < 576) { src = Wo;  K = 768;  N = 768;  ooff = 1769472; t = bid - 432; }
  else if (bid < 1152){ src = W1;  K = 768;  N = 3072; ooff = 2359296; t = bid - 576; }
  else                { src = W2;  K = 3072; N = 768;  ooff = 4718592; t = bid - 1152; }
  if (!wp_only) src += (size_t)layer * K * N;
  int ntn = N >> 6;
  int tk = t / ntn, tn = t % ntn;
  int k0 = tk * 64, n0 = tn * 64;

  __shared__ unsigned lp[32][66];
  const int tid = threadIdx.x;
  #pragma unroll
  for (int p = 0; p < 2; p++){
    int rp = p * 16 + (tid >> 4);
    int c  = (tid & 15) * 4;
    const float* s0 = src + (size_t)(k0 + 2 * rp) * N + n0 + c;
    float4 a = *(const float4*)s0;
    float4 b = *(const float4*)(s0 + N);
    unsigned u0 = pk2h(a.x, b.x), u1 = pk2h(a.y, b.y);
    unsigned u2 = pk2h(a.z, b.z), u3 = pk2h(a.w, b.w);
    *(uint4*)&lp[rp][c] = make_uint4(u0, u1, u2, u3);
  }
  __syncthreads();
  #pragma unroll
  for (int p = 0; p < 2; p++){
    int n = p * 32 + (tid >> 3);
    int q = tid & 7;
    unsigned u[4];
    #pragma unroll
    for (int j = 0; j < 4; j++) u[j] = lp[q * 4 + j][n];
    *(uint4*)(th + ooff + (size_t)(n0 + n) * K + k0 + q * 8)
        = make_uint4(u[0], u[1], u[2], u[3]);
  }
}

__global__ __launch_bounds__(256) void convert_w_kernel(
    const float* __restrict__ Wq, const float* __restrict__ Wkv,
    const float* __restrict__ Wo, const float* __restrict__ W1,
    const float* __restrict__ W2, int layer, int wp_only,
    f16* __restrict__ th)
{
  convert_body(blockIdx.x, Wq, Wkv, Wo, W1, W2, layer, wp_only, th);
}

// ------------- big GEMM body: 128x128 block, 4 waves of 64x64, BK=128 --------
// single-buffer LDS (64KB: 2x32KB), XOR-swizzled via pre-swizzled
// global_load_lds source; halved K-steps amortize the per-step barrier drain
// (grid-limited occupancy, so the larger LDS costs nothing).
// mode 1: f16 gelu(acc+bias) -> Cq[N]
// mode 2: qkv epilogue (fused qk-rmsnorm, gammas folded into Q)
// mode 3: split-K f16 partial -> Cq + z*NTOK*N
__device__ __forceinline__ void gemm_big_body(
    int bid, int bz, int nz,
    const f16* __restrict__ Aq, const f16* __restrict__ Bw,
    const float* __restrict__ bias,
    f16* __restrict__ Cq,
    f16* __restrict__ Qh, f16* __restrict__ Kt, f16* __restrict__ Vt,
    const float* __restrict__ qgam, const float* __restrict__ kgam,
    int N, int K, int nbx, int mode)
{
  __shared__ __align__(16) f16 sA[128 * 128];
  __shared__ __align__(16) f16 sB[128 * 128];
  const int tid = threadIdx.x;
  const int wid = tid >> 6, lane = tid & 63;
  const int nwg = nbx << 4;
  const int swz = (bid & 7) * (nwg >> 3) + (bid >> 3);
  const int by = swz & 15, bx = swz >> 4;
  const int brow = by << 7, bcol = bx << 7;
  const int m2 = wid & 1, n2 = wid >> 1;
  const int fr = lane & 15, fq = lane >> 4;
  const int Kc = K / nz;
  const int kbase = bz * Kc;
  const int nk = Kc >> 7;

  const f16* pA = Aq + (size_t)brow * K + kbase;
  const f16* pB = Bw + (size_t)bcol * K + kbase;

  f32x4 acc[4][4] = {};

  for (int ks = 0; ks < nk; ks++){
    const int k0 = ks << 7;
    if (ks) __syncthreads();
    // stage A,B: 128 rows x 128 k each (16 chunks of 16B per row), 8 passes
    #pragma unroll
    for (int i = 0; i < 8; i++){
      int idx = tid + i * 256;
      int r = idx >> 4, c = idx & 15;
      int gc = c ^ (r & 7);             // XOR on low 3 bits of chunk index
      gload16(pA + (size_t)r * K + k0 + gc * 8, &sA[idx * 8]);
      gload16(pB + (size_t)r * K + k0 + gc * 8, &sB[idx * 8]);
    }
    __syncthreads();
    #pragma unroll
    for (int s = 0; s < 4; s++){
      f16x8 a[4], b[4];
      #pragma unroll
      for (int m = 0; m < 4; m++){
        int r = m2 * 64 + m * 16 + fr;
        int ch = (s * 4 + fq) ^ (r & 7);
        a[m] = *(const f16x8*)(&sA[r * 128 + ch * 8]);
      }
      #pragma unroll
      for (int n = 0; n < 4; n++){
        int r = n2 * 64 + n * 16 + fr;
        int ch = (s * 4 + fq) ^ (r & 7);
        b[n] = *(const f16x8*)(&sB[r * 128 + ch * 8]);
      }
      #pragma unroll
      for (int m = 0; m < 4; m++)
        #pragma unroll
        for (int n = 0; n < 4; n++)
          acc[m][n] = __builtin_amdgcn_mfma_f32_16x16x32_f16(a[m], b[n], acc[m][n], 0, 0, 0);
    }
  }

  // epilogue: D layout col=lane&15, row=(lane>>4)*4+i
  if (mode == 2){
    const int hbase = bcol + n2 * 64;   // wave-uniform, 64-aligned head block
    if (hbase < 768){
      float gp[4];
      #pragma unroll
      for (int n = 0; n < 4; n++){
        int col = hbase + n * 16 + fr;
        gp[n] = qgam[col] * kgam[col];
      }
      #pragma unroll
      for (int m = 0; m < 4; m++)
        #pragma unroll
        for (int i = 0; i < 4; i++){
          float s = 0.f;
          #pragma unroll
          for (int n = 0; n < 4; n++) s += acc[m][n][i] * acc[m][n][i];
          s += __shfl_xor(s, 1); s += __shfl_xor(s, 2);
          s += __shfl_xor(s, 4); s += __shfl_xor(s, 8);
          float f = 8.f / fmaxf(sqrtf(s), 1e-12f);
          int row = brow + m2 * 64 + m * 16 + (fq << 2) + i;
          #pragma unroll
          for (int n = 0; n < 4; n++)
            Qh[(size_t)row * 768 + hbase + n * 16 + fr] = (f16)(acc[m][n][i] * f * gp[n]);
        }
    } else if (hbase < 1536){
      int hh = (hbase - 768) >> 6;
      #pragma unroll
      for (int m = 0; m < 4; m++)
        #pragma unroll
        for (int i = 0; i < 4; i++){
          float s = 0.f;
          #pragma unroll
          for (int n = 0; n < 4; n++) s += acc[m][n][i] * acc[m][n][i];
          s += __shfl_xor(s, 1); s += __shfl_xor(s, 2);
          s += __shfl_xor(s, 4); s += __shfl_xor(s, 8);
          float f = 8.f / fmaxf(sqrtf(s), 1e-12f);
          int row = brow + m2 * 64 + m * 16 + (fq << 2) + i;
          int bq = row >> 10, tok = row & 1023;
          #pragma unroll
          for (int n = 0; n < 4; n++)
            Kt[((size_t)(bq * 12 + hh) * 1024 + tok) * 64 + n * 16 + fr]
                = (f16)(acc[m][n][i] * f);
        }
    } else {
      int hh = (hbase - 1536) >> 6;
      #pragma unroll
      for (int n = 0; n < 4; n++){
        int dd = n * 16 + fr;
        #pragma unroll
        for (int m = 0; m < 4; m++){
          int row0 = brow + m2 * 64 + m * 16 + (fq << 2);
          int bq = row0 >> 10, tok0 = row0 & 1023;
          ushort4 sv;
          sv.x = h2u((f16)acc[m][n][0]); sv.y = h2u((f16)acc[m][n][1]);
          sv.z = h2u((f16)acc[m][n][2]); sv.w = h2u((f16)acc[m][n][3]);
          *(ushort4*)(Vt + ((size_t)((bq * 12 + hh) * 64 + dd)) * 1024 + tok0) = sv;
        }
      }
    }
  } else if (mode == 1){
    #pragma unroll
    for (int n = 0; n < 4; n++){
      int col = bcol + n2 * 64 + n * 16 + fr;
      float bv = bias[col];
      #pragma unroll
      for (int m = 0; m < 4; m++){
        int row0 = brow + m2 * 64 + m * 16 + (fq << 2);
        #pragma unroll
        for (int i = 0; i < 4; i++){
          float v = acc[m][n][i] + bv;
          float ge = 0.5f * v * (1.f + erff(v * 0.70710678118654752f));
          Cq[(size_t)(row0 + i) * N + col] = (f16)ge;
        }
      }
    }
  } else {  // mode 3: f16 split-K partials
    f16* P = Cq + (size_t)bz * ((size_t)NTOK * N);
    #pragma unroll
    for (int n = 0; n < 4; n++){
      int col = bcol + n2 * 64 + n * 16 + fr;
      #pragma unroll
      for (int m = 0; m < 4; m++){
        int row0 = brow + m2 * 64 + m * 16 + (fq << 2);
        #pragma unroll
        for (int i = 0; i < 4; i++)
          P[(size_t)(row0 + i) * N + col] = (f16)acc[m][n][i];
      }
    }
  }
}

__global__ __launch_bounds__(256) void gemm_big(
    const f16* __restrict__ Aq, const f16* __restrict__ Bw,
    const float* __restrict__ bias,
    f16* __restrict__ Cq,
    f16* __restrict__ Qh, f16* __restrict__ Kt, f16* __restrict__ Vt,
    const float* __restrict__ qgam, const float* __restrict__ kgam,
    int N, int K, int nbx, int mode)
{
  gemm_big_body(blockIdx.x, blockIdx.z, (int)gridDim.z,
                Aq, Bw, bias, Cq, Qh, Kt, Vt, qgam, kgam, N, K, nbx, mode);
}

// ------ merged: qkv projection (blocks 0-287) + next-layer convert (288+) ----
__global__ __launch_bounds__(256) void qkvconv_kernel(
    const f16* __restrict__ Aq, const f16* __restrict__ Bw,
    f16* __restrict__ Qh, f16* __restrict__ Kt, f16* __restrict__ Vt,
    const float* __restrict__ qgam, const float* __restrict__ kgam,
    const float* __restrict__ Wq, const float* __restrict__ Wkv,
    const float* __restrict__ Wo, const float* __restrict__ W1,
    const float* __restrict__ W2, int nlayer, f16* __restrict__ thn)
{
  if (blockIdx.x < 288)
    gemm_big_body((int)blockIdx.x, 0, 1, Aq, Bw, nullptr, nullptr,
                  Qh, Kt, Vt, qgam, kgam, 3 * DIM, DIM, 18, 2);
  else if (nlayer >= 0)
    convert_body((int)blockIdx.x - 288, Wq, Wkv, Wo, W1, W2, nlayer, 0, thn);
}

// ------------- small GEMM (64x64 block, 4 waves of 32x32): f32 out -----------
__global__ __launch_bounds__(256) void gemm_small(
    const f16* __restrict__ Aq, const f16* __restrict__ Bw,
    const float* __restrict__ bias, const float* __restrict__ res,
    float* __restrict__ C, int N, int K, int nbx)
{
  __shared__ __align__(16) f16 sA[2][64 * 64];
  __shared__ __align__(16) f16 sB[2][64 * 64];
  const int tid = threadIdx.x;
  const int wid = tid >> 6, lane = tid & 63;
  const int nwg = nbx << 5;
  const int bid = blockIdx.x;
  const int swz = (bid & 7) * (nwg >> 3) + (bid >> 3);
  const int by = swz & 31, bx = swz >> 5;
  const int brow = by << 6, bcol = bx << 6;
  const int m2 = wid & 1, n2 = wid >> 1;
  const int fr = lane & 15, fq = lane >> 4;
  const int nk = K >> 6;

  const f16* pA = Aq + (size_t)brow * K;
  const f16* pB = Bw + (size_t)bcol * K;

  f32x4 acc[2][2] = {};

  auto STAGE = [&](int buf, int ks){
    const int k0 = ks << 6;
    #pragma unroll
    for (int i = 0; i < 2; i++){
      int idx = tid + i * 256;
      int r = idx >> 3, c = idx & 7;
      int gc = c ^ (r & 7);
      gload16(pA + (size_t)r * K + k0 + gc * 8, &sA[buf][idx * 8]);
      gload16(pB + (size_t)r * K + k0 + gc * 8, &sB[buf][idx * 8]);
    }
  };

  STAGE(0, 0);
  __syncthreads();
  int cur = 0;
  for (int ks = 0; ks < nk; ks++){
    if (ks + 1 < nk) STAGE(cur ^ 1, ks + 1);
    #pragma unroll
    for (int s = 0; s < 2; s++){
      f16x8 a[2], b[2];
      #pragma unroll
      for (int m = 0; m < 2; m++){
        int r = m2 * 32 + m * 16 + fr;
        int ch = (s * 4 + fq) ^ (r & 7);
        a[m] = *(const f16x8*)(&sA[cur][r * 64 + ch * 8]);
      }
      #pragma unroll
      for (int n = 0; n < 2; n++){
        int r = n2 * 32 + n * 16 + fr;
        int ch = (s * 4 + fq) ^ (r & 7);
        b[n] = *(const f16x8*)(&sB[cur][r * 64 + ch * 8]);
      }
      #pragma unroll
      for (int m = 0; m < 2; m++)
        #pragma unroll
        for (int n = 0; n < 2; n++)
          acc[m][n] = __builtin_amdgcn_mfma_f32_16x16x32_f16(a[m], b[n], acc[m][n], 0, 0, 0);
    }
    __syncthreads();
    cur ^= 1;
  }

  #pragma unroll
  for (int n = 0; n < 2; n++){
    int col = bcol + n2 * 32 + n * 16 + fr;
    float bv = bias ? bias[col] : 0.f;
    #pragma unroll
    for (int m = 0; m < 2; m++){
      int row0 = brow + m2 * 32 + m * 16 + (fq << 2);
      #pragma unroll
      for (int i = 0; i < 4; i++){
        float v = acc[m][n][i] + bv;
        size_t o = (size_t)(row0 + i) * N + col;
        if (res) v += res[o];
        C[o] = v;
      }
    }
  }
}

// ------- fused (optional 4-way f16 split-K reduce + badd + residual) + LN ----
__global__ __launch_bounds__(256) void lnred_kernel(
    float* __restrict__ x, const f16* __restrict__ p, const float* __restrict__ badd,
    int npart, const float* __restrict__ g, f16* __restrict__ yq, float* __restrict__ yf)
{
  int wid = threadIdx.x >> 6, lane = threadIdx.x & 63;
  int row = blockIdx.x * 4 + wid;
  float* xr = x + (size_t)row * DIM;
  float v[12]; float s = 0.f;
  if (npart){
    #pragma unroll
    for (int d = 0; d < 12; d++){
      int c = d * 64 + lane;
      float t = xr[c] + badd[c];
      #pragma unroll
      for (int j = 0; j < 4; j++)
        t += (float)p[(size_t)j * (NTOK * DIM) + (size_t)row * DIM + c];
      xr[c] = t; v[d] = t; s += t;
    }
  } else {
    #pragma unroll
    for (int d = 0; d < 12; d++){ v[d] = xr[d * 64 + lane]; s += v[d]; }
  }
  s = wred_sum(s);
  float mean = s * (1.f / 768.f);
  float q2 = 0.f;
  #pragma unroll
  for (int d = 0; d < 12; d++){ float t = v[d] - mean; q2 += t * t; }
  q2 = wred_sum(q2);
  float rstd = rsqrtf(q2 * (1.f / 768.f) + 1e-5f);
  size_t base = (size_t)row * DIM;
  #pragma unroll
  for (int d = 0; d < 12; d++){
    float y = (v[d] - mean) * rstd * g[d * 64 + lane];
    if (yq) yq[base + d * 64 + lane] = (f16)y;
    else    yf[base + d * 64 + lane] = y;
  }
}

// ---------------- pos-embed add -> f16 ---------------------------------------
__global__ __launch_bounds__(256) void posadd_kernel(
    const float* __restrict__ patches, const int* __restrict__ hi,
    const int* __restrict__ wi, const float* __restrict__ ph,
    const float* __restrict__ pw, f16* __restrict__ oq)
{
  int idx = blockIdx.x * 256 + threadIdx.x;
  int tok = idx / 192, cv = idx % 192;
  float4 p = ((const float4*)patches)[idx];
  float4 a = *(const float4*)(ph + (size_t)hi[tok] * DIM + cv * 4);
  float4 b = *(const float4*)(pw + (size_t)wi[tok] * DIM + cv * 4);
  ushort4 o;
  o.x = h2u((f16)(p.x + a.x + b.x)); o.y = h2u((f16)(p.y + a.y + b.y));
  o.z = h2u((f16)(p.z + a.z + b.z)); o.w = h2u((f16)(p.w + a.w + b.w));
  ((ushort4*)oq)[idx] = o;
}

// ---------------- segment ranges from sorted image_ids -----------------------
__global__ void seg_kernel(const int* __restrict__ ids, int2* __restrict__ segs)
{
  int i = blockIdx.x * 256 + threadIdx.x;
  int b = blockIdx.y;
  const int* row = ids + b * SEQ;
  int v = row[i];
  int lo = 0, hi = SEQ;
  while (lo < hi){ int mid = (lo + hi) >> 1; if (row[mid] <  v) lo = mid + 1; else hi = mid; }
  int s = lo;
  lo = 0; hi = SEQ;
  while (lo < hi){ int mid = (lo + hi) >> 1; if (row[mid] <= v) lo = mid + 1; else hi = mid; }
  segs[b * SEQ + i] = make_int2(s, lo);
}

// --------- MFMA flash attention over segments (all-f16, KVBLK=64) ------------
// grid = (qt, bh): consecutive blocks share one (b,h) K/V panel -> L2 locality.
__global__ __launch_bounds__(256) void attn_kernel(
    const f16* __restrict__ qh, const f16* __restrict__ ktp,
    const f16* __restrict__ vt, const int2* __restrict__ segs,
    f16* __restrict__ oq)
{
  __shared__ __align__(16) ushort_t Kq[64 * 64];    // 8 KB, XOR-swizzled rows
  __shared__ __align__(16) ushort_t Vl[64 * 72];    // 9 KB, [d][key] stride 144B

  const int tid = threadIdx.x;
  const int w = tid >> 6, lane = tid & 63;
  const int q15 = lane & 15, kg = lane >> 4;
  const int bh = blockIdx.y, b = bh / 12, h = bh % 12;
  const int qt = blockIdx.x;
  const int qrow = qt * 64 + w * 16 + q15;
  const size_t qtok = (size_t)b * SEQ + qrow;

  const f16* qp = qh + qtok * DIM + h * 64 + kg * 8;
  f16x8 qf[2];
  qf[0] = *(const f16x8*)(qp);
  qf[1] = *(const f16x8*)(qp + 32);

  const int2 se  = segs[qtok];
  const int2 se0 = segs[(size_t)b * SEQ + qt * 64];
  const int2 se1 = segs[(size_t)b * SEQ + qt * 64 + 63];
  const int klo = se0.x & ~63, khi = se1.y;

  float m = -3.0e38f, l = 0.f;
  f32x4 oacc[4] = {};

  const f16* kbase = ktp + (size_t)bh * 1024 * 64;
  const int vd = tid >> 2, vc0 = tid & 3;

  for (int kt0 = klo; kt0 < khi; kt0 += 64){
    #pragma unroll
    for (int i = 0; i < 2; i++){
      int idx = tid + i * 256;
      int r = idx >> 3, c = idx & 7;
      int gc = c ^ (r & 7);
      gload16(kbase + (size_t)(kt0 + r) * 64 + gc * 8, Kq + idx * 8);
    }
    #pragma unroll
    for (int p2 = 0; p2 < 2; p2++){
      int chunk = vc0 + p2 * 4;
      uint4 vv = *(const uint4*)(vt + ((size_t)bh * 64 + vd) * SEQ + kt0 + chunk * 8);
      *(uint4*)((char*)Vl + vd * 144 + chunk * 16) = vv;
    }
    __syncthreads();

    f32x4 s[4] = {};
    #pragma unroll
    for (int dh2 = 0; dh2 < 2; dh2++){
      #pragma unroll
      for (int khf = 0; khf < 4; khf++){
        int row = khf * 16 + q15;
        unsigned off = ((unsigned)row << 7) + ((unsigned)(dh2 * 4 + kg) << 4);
        off ^= (unsigned)(row & 7) << 4;
        f16x8 kf = *(const f16x8*)((const char*)Kq + off);
        s[khf] = __builtin_amdgcn_mfma_f32_16x16x32_f16(kf, qf[dh2], s[khf], 0, 0, 0);
      }
    }

    float p[16]; float tmax = -3.0e38f;
    #pragma unroll
    for (int khf = 0; khf < 4; khf++)
      #pragma unroll
      for (int i = 0; i < 4; i++){
        int key = kt0 + khf * 16 + kg * 4 + i;
        bool val = (key >= se.x) && (key < se.y);
        float sv = val ? s[khf][i] : -3.0e38f;
        p[khf * 4 + i] = sv;
        tmax = fmaxf(tmax, sv);
      }
    tmax = fmaxf(tmax, __shfl_xor(tmax, 16));
    tmax = fmaxf(tmax, __shfl_xor(tmax, 32));
    float mnew = fmaxf(m, tmax);
    float sc = __expf(m - mnew);
    float psum = 0.f;
    #pragma unroll
    for (int j = 0; j < 16; j++){
      float pv = (p[j] > -1.0e38f) ? __expf(p[j] - mnew) : 0.f;
      p[j] = pv; psum += pv;
    }
    psum += __shfl_xor(psum, 16);
    psum += __shfl_xor(psum, 32);
    l = l * sc + psum;
    m = mnew;
    #pragma unroll
    for (int dt = 0; dt < 4; dt++) oacc[dt] *= sc;

    int s0l = q15 + ((kg & 1) << 5);
    int s1l = s0l + 16;
    bool hih = kg >= 2;
    unsigned uA0 = pk2h(p[0],  p[1]),  uA1 = pk2h(p[2],  p[3]);
    unsigned uA2 = pk2h(p[4],  p[5]),  uA3 = pk2h(p[6],  p[7]);
    unsigned uB0 = pk2h(p[8],  p[9]),  uB1 = pk2h(p[10], p[11]);
    unsigned uB2 = pk2h(p[12], p[13]), uB3 = pk2h(p[14], p[15]);
    unsigned a0 = __shfl(uA0, s0l), b0 = __shfl(uA1, s0l);
    unsigned a1 = __shfl(uA0, s1l), b1 = __shfl(uA1, s1l);
    unsigned c0 = __shfl(uA2, s0l), d0 = __shfl(uA3, s0l);
    unsigned c1 = __shfl(uA2, s1l), d1 = __shfl(uA3, s1l);
    f16x8 pfA = __builtin_bit_cast(f16x8,
        make_uint4(hih ? c0 : a0, hih ? d0 : b0, hih ? c1 : a1, hih ? d1 : b1));
    unsigned e0 = __shfl(uB0, s0l), f0 = __shfl(uB1, s0l);
    unsigned e1 = __shfl(uB0, s1l), f1 = __shfl(uB1, s1l);
    unsigned g0 = __shfl(uB2, s0l), h0 = __shfl(uB3, s0l);
    unsigned g1 = __shfl(uB2, s1l), h1 = __shfl(uB3, s1l);
    f16x8 pfB = __builtin_bit_cast(f16x8,
        make_uint4(hih ? g0 : e0, hih ? h0 : f0, hih ? g1 : e1, hih ? h1 : f1));

    #pragma unroll
    for (int dt = 0; dt < 4; dt++){
      const char* vb = (const char*)Vl + (dt * 16 + q15) * 144 + kg * 16;
      f16x8 vfA = *(const f16x8*)vb;
      f16x8 vfB = *(const f16x8*)(vb + 64);
      oacc[dt] = __builtin_amdgcn_mfma_f32_16x16x32_f16(vfA, pfA, oacc[dt], 0, 0, 0);
      oacc[dt] = __builtin_amdgcn_mfma_f32_16x16x32_f16(vfB, pfB, oacc[dt], 0, 0, 0);
    }
    __syncthreads();
  }

  float rl = 1.f / l;
  size_t obase = qtok * DIM + h * 64;
  #pragma unroll
  for (int dt = 0; dt < 4; dt++){
    ushort4 hs;
    hs.x = h2u((f16)(oacc[dt][0] * rl)); hs.y = h2u((f16)(oacc[dt][1] * rl));
    hs.z = h2u((f16)(oacc[dt][2] * rl)); hs.w = h2u((f16)(oacc[dt][3] * rl));
    *(ushort4*)(oq + obase + dt * 16 + kg * 4) = hs;
  }
}

// ---------------- driver -----------------------------------------------------
extern "C" void kernel_launch(void* const* d_in, const int* in_sizes, int n_in,
                              void* d_out, int out_size, void* d_ws, size_t ws_size,
                              hipStream_t stream)
{
  const float* patches   = (const float*)d_in[0];
  const int*   h_idx     = (const int*)d_in[1];
  const int*   w_idx     = (const int*)d_in[2];
  const int*   image_ids = (const int*)d_in[3];
  const float* pos_h = (const float*)d_in[4];
  const float* pos_w = (const float*)d_in[5];
  const float* Wp  = (const float*)d_in[6];
  const float* bp  = (const float*)d_in[7];
  const float* lnp = (const float*)d_in[8];
  const float* ln1 = (const float*)d_in[9];
  const float* qg  = (const float*)d_in[10];
  const float* kg  = (const float*)d_in[11];
  const float* Wq  = (const float*)d_in[12];
  const float* Wkv = (const float*)d_in[13];
  const float* Wo  = (const float*)d_in[14];
  const float* ln2 = (const float*)d_in[15];
  const float* W1  = (const float*)d_in[16];
  const float* b1  = (const float*)d_in[17];
  const float* W2  = (const float*)d_in[18];
  const float* b2  = (const float*)d_in[19];
  const float* lnf = (const float*)d_in[20];
  float* out = (float*)d_out;

  char* w = (char*)d_ws;
  float* x = (float*)w;            w += (size_t)NTOK * DIM * 4;
  f16* pbufh = (f16*)w;            w += (size_t)4 * NTOK * DIM * 2;   // split-K partials / Wp weights
  f16* qh  = (f16*)w;              w += (size_t)NTOK * DIM * 2;
  f16* ktb = (f16*)w;              w += (size_t)NTOK * DIM * 2;
  f16* vtb = (f16*)w;              w += (size_t)NTOK * DIM * 2;
  f16* aAq = (f16*)w;              w += (size_t)NTOK * DIM * 2;
  f16* aBq = (f16*)w;              w += (size_t)NTOK * MLP_ * 2;      // also f32 tmp
  int2* segs = (int2*)w;           w += (size_t)NTOK * 8;
  f16* wlA = (f16*)w;              w += (size_t)WELTS * 2;            // alternating hot
  f16* wlB = (f16*)w;                                                  // weight buffers
  float* ptmp = (float*)aBq;       // 2048*768 f32 fits in aBq region
  f16* wpc = pbufh;                // Wp converted (1.2MB) — dead until first W2

  seg_kernel<<<dim3(4, 2), 256, 0, stream>>>(image_ids, segs);
  posadd_kernel<<<1536, 256, 0, stream>>>(patches, h_idx, w_idx, pos_h, pos_w, aAq);
  convert_w_kernel<<<144, 256, 0, stream>>>(Wp, nullptr, nullptr, nullptr, nullptr, 0, 1, wpc);
  gemm_small<<<384, 256, 0, stream>>>(aAq, wpc, bp, nullptr, ptmp, DIM, DIM, 12);
  lnred_kernel<<<NTOK / 4, 256, 0, stream>>>(ptmp, nullptr, nullptr, 0, lnp, nullptr, x);
  convert_w_kernel<<<1728, 256, 0, stream>>>(Wq, Wkv, Wo, W1, W2, 0, 0, wlA);

  for (int i = 0; i < 8; i++){
    f16* wcur = (i & 1) ? wlB : wlA;
    f16* wnxt = (i & 1) ? wlA : wlB;
    // fused: x += (prev-layer W2 partials + b2) ; ln1 -> aAq (f16)
    lnred_kernel<<<NTOK / 4, 256, 0, stream>>>(
        x, pbufh, i ? (b2 + (i - 1) * DIM) : nullptr, i ? 4 : 0,
        ln1 + i * DIM, aAq, nullptr);
    // merged: qkv projection (+fused rmsnorm) || next-layer weight convert
    qkvconv_kernel<<<2016, 256, 0, stream>>>(
        aAq, wcur, qh, ktb, vtb, qg + i * DIM, kg + i * DIM,
        Wq, Wkv, Wo, W1, W2, (i < 7) ? i + 1 : -1, wnxt);
    attn_kernel<<<dim3(16, 24), 256, 0, stream>>>(qh, ktb, vtb, segs, aAq);
    gemm_small<<<384, 256, 0, stream>>>(
        aAq, wcur + 1769472, nullptr, x, x, DIM, DIM, 12);
    lnred_kernel<<<NTOK / 4, 256, 0, stream>>>(
        x, nullptr, nullptr, 0, ln2 + i * DIM, aAq, nullptr);
    gemm_big<<<384, 256, 0, stream>>>(
        aAq, wcur + 2359296, b1 + i * MLP_, aBq, nullptr, nullptr, nullptr,
        nullptr, nullptr, MLP_, DIM, 24, 1);
    gemm_big<<<dim3(96, 1, 4), 256, 0, stream>>>(
        aBq, wcur + 4718592, nullptr, pbufh, nullptr, nullptr, nullptr,
        nullptr, nullptr, DIM, MLP_, 6, 3);
  }
  lnred_kernel<<<NTOK / 4, 256, 0, stream>>>(x, pbufh, b2 + 7 * DIM, 4, lnf, nullptr, out);
}

// Round 17
// 872.927 us; speedup vs baseline: 1.4260x; 1.0101x over previous
//
#include <hip/hip_runtime.h>
#include <hip/hip_bf16.h>
#include <math.h>

typedef _Float16 f16;
typedef f16   f16x8 __attribute__((ext_vector_type(8)));
typedef float f32x4 __attribute__((ext_vector_type(4)));
typedef unsigned short ushort_t;

#define DIM   768
#define HEADS 12
#define DH    64
#define MLP_  3072
#define NTOK  2048
#define SEQ   1024
#define WELTS 7077888   // per-layer converted weight elements (Wq+Wkv+Wo+W1+W2)

__device__ __forceinline__ ushort_t h2u(f16 h){ return __builtin_bit_cast(ushort_t, h); }
__device__ __forceinline__ unsigned pk2h(float a, float b){
  return (unsigned)h2u((f16)a) | ((unsigned)h2u((f16)b) << 16);
}
__device__ __forceinline__ void gload16(const void* g, void* l){
  __builtin_amdgcn_global_load_lds(
      (const __attribute__((address_space(1))) void*)g,
      (__attribute__((address_space(3))) void*)l, 16, 0, 0);
}
__device__ __forceinline__ float wred_sum(float v){
  #pragma unroll
  for (int o = 32; o > 0; o >>= 1) v += __shfl_xor(v, o);
  return v;
}

// ---------- weight convert body: W[K][N] f32 -> Wt [N][K] f16 ----------------
__device__ __forceinline__ void convert_body(
    int bid, const float* __restrict__ Wq, const float* __restrict__ Wkv,
    const float* __restrict__ Wo, const float* __restrict__ W1,
    const float* __restrict__ W2, int layer, int wp_only,
    f16* __restrict__ th)
{
  const float* src; int K, N; size_t ooff; int t;
  if (wp_only){ src = Wq; K = 768; N = 768; ooff = 0; t = bid; }
  else if (bid < 144) { src = Wq;  K = 768;  N = 768;  ooff = 0;       t = bid; }
  else if (bid < 432) { src = Wkv; K = 768;  N = 1536; ooff = 589824;  t = bid - 144; }
  else if (bid < 576) { src = Wo;  K = 768;  N = 768;  ooff = 1769472; t = bid - 432; }
  else if (bid < 1152){ src = W1;  K = 768;  N = 3072; ooff = 2359296; t = bid - 576; }
  else                { src = W2;  K = 3072; N = 768;  ooff = 4718592; t = bid - 1152; }
  if (!wp_only) src += (size_t)layer * K * N;
  int ntn = N >> 6;
  int tk = t / ntn, tn = t % ntn;
  int k0 = tk * 64, n0 = tn * 64;

  __shared__ unsigned lp[32][66];
  const int tid = threadIdx.x;
  #pragma unroll
  for (int p = 0; p < 2; p++){
    int rp = p * 16 + (tid >> 4);
    int c  = (tid & 15) * 4;
    const float* s0 = src + (size_t)(k0 + 2 * rp) * N + n0 + c;
    float4 a = *(const float4*)s0;
    float4 b = *(const float4*)(s0 + N);
    unsigned u0 = pk2h(a.x, b.x), u1 = pk2h(a.y, b.y);
    unsigned u2 = pk2h(a.z, b.z), u3 = pk2h(a.w, b.w);
    *(uint4*)&lp[rp][c] = make_uint4(u0, u1, u2, u3);
  }
  __syncthreads();
  #pragma unroll
  for (int p = 0; p < 2; p++){
    int n = p * 32 + (tid >> 3);
    int q = tid & 7;
    unsigned u[4];
    #pragma unroll
    for (int j = 0; j < 4; j++) u[j] = lp[q * 4 + j][n];
    *(uint4*)(th + ooff + (size_t)(n0 + n) * K + k0 + q * 8)
        = make_uint4(u[0], u[1], u[2], u[3]);
  }
}

__global__ __launch_bounds__(256) void convert_w_kernel(
    const float* __restrict__ Wq, const float* __restrict__ Wkv,
    const float* __restrict__ Wo, const float* __restrict__ W1,
    const float* __restrict__ W2, int layer, int wp_only,
    f16* __restrict__ th)
{
  convert_body(blockIdx.x, Wq, Wkv, Wo, W1, W2, layer, wp_only, th);
}

// ------------- big GEMM body: 128x128 block, 4 waves of 64x64, BK=128 --------
// single-buffer LDS (64KB), XOR-swizzled via pre-swizzled global_load_lds src;
// halved K-steps amortize the per-step barrier drain (grid-limited occupancy).
// mode 1: f16 gelu(acc+bias) -> Cq[N]
// mode 2: qkv epilogue (fused qk-rmsnorm, gammas folded into Q)
// mode 3: split-K f16 partial -> Cq + z*NTOK*N
__device__ __forceinline__ void gemm_big_body(
    int bid, int bz, int nz,
    const f16* __restrict__ Aq, const f16* __restrict__ Bw,
    const float* __restrict__ bias,
    f16* __restrict__ Cq,
    f16* __restrict__ Qh, f16* __restrict__ Kt, f16* __restrict__ Vt,
    const float* __restrict__ qgam, const float* __restrict__ kgam,
    int N, int K, int nbx, int mode)
{
  __shared__ __align__(16) f16 sA[128 * 128];
  __shared__ __align__(16) f16 sB[128 * 128];
  const int tid = threadIdx.x;
  const int wid = tid >> 6, lane = tid & 63;
  const int nwg = nbx << 4;
  const int swz = (bid & 7) * (nwg >> 3) + (bid >> 3);
  const int by = swz & 15, bx = swz >> 4;
  const int brow = by << 7, bcol = bx << 7;
  const int m2 = wid & 1, n2 = wid >> 1;
  const int fr = lane & 15, fq = lane >> 4;
  const int Kc = K / nz;
  const int kbase = bz * Kc;
  const int nk = Kc >> 7;

  const f16* pA = Aq + (size_t)brow * K + kbase;
  const f16* pB = Bw + (size_t)bcol * K + kbase;

  f32x4 acc[4][4] = {};

  for (int ks = 0; ks < nk; ks++){
    const int k0 = ks << 7;
    if (ks) __syncthreads();
    #pragma unroll
    for (int i = 0; i < 8; i++){
      int idx = tid + i * 256;
      int r = idx >> 4, c = idx & 15;
      int gc = c ^ (r & 7);
      gload16(pA + (size_t)r * K + k0 + gc * 8, &sA[idx * 8]);
      gload16(pB + (size_t)r * K + k0 + gc * 8, &sB[idx * 8]);
    }
    __syncthreads();
    #pragma unroll
    for (int s = 0; s < 4; s++){
      f16x8 a[4], b[4];
      #pragma unroll
      for (int m = 0; m < 4; m++){
        int r = m2 * 64 + m * 16 + fr;
        int ch = (s * 4 + fq) ^ (r & 7);
        a[m] = *(const f16x8*)(&sA[r * 128 + ch * 8]);
      }
      #pragma unroll
      for (int n = 0; n < 4; n++){
        int r = n2 * 64 + n * 16 + fr;
        int ch = (s * 4 + fq) ^ (r & 7);
        b[n] = *(const f16x8*)(&sB[r * 128 + ch * 8]);
      }
      #pragma unroll
      for (int m = 0; m < 4; m++)
        #pragma unroll
        for (int n = 0; n < 4; n++)
          acc[m][n] = __builtin_amdgcn_mfma_f32_16x16x32_f16(a[m], b[n], acc[m][n], 0, 0, 0);
    }
  }

  // epilogue: D layout col=lane&15, row=(lane>>4)*4+i
  if (mode == 2){
    const int hbase = bcol + n2 * 64;   // wave-uniform, 64-aligned head block
    if (hbase < 768){
      float gp[4];
      #pragma unroll
      for (int n = 0; n < 4; n++){
        int col = hbase + n * 16 + fr;
        gp[n] = qgam[col] * kgam[col];
      }
      #pragma unroll
      for (int m = 0; m < 4; m++)
        #pragma unroll
        for (int i = 0; i < 4; i++){
          float s = 0.f;
          #pragma unroll
          for (int n = 0; n < 4; n++) s += acc[m][n][i] * acc[m][n][i];
          s += __shfl_xor(s, 1); s += __shfl_xor(s, 2);
          s += __shfl_xor(s, 4); s += __shfl_xor(s, 8);
          float f = 8.f / fmaxf(sqrtf(s), 1e-12f);
          int row = brow + m2 * 64 + m * 16 + (fq << 2) + i;
          #pragma unroll
          for (int n = 0; n < 4; n++)
            Qh[(size_t)row * 768 + hbase + n * 16 + fr] = (f16)(acc[m][n][i] * f * gp[n]);
        }
    } else if (hbase < 1536){
      int hh = (hbase - 768) >> 6;
      #pragma unroll
      for (int m = 0; m < 4; m++)
        #pragma unroll
        for (int i = 0; i < 4; i++){
          float s = 0.f;
          #pragma unroll
          for (int n = 0; n < 4; n++) s += acc[m][n][i] * acc[m][n][i];
          s += __shfl_xor(s, 1); s += __shfl_xor(s, 2);
          s += __shfl_xor(s, 4); s += __shfl_xor(s, 8);
          float f = 8.f / fmaxf(sqrtf(s), 1e-12f);
          int row = brow + m2 * 64 + m * 16 + (fq << 2) + i;
          int bq = row >> 10, tok = row & 1023;
          #pragma unroll
          for (int n = 0; n < 4; n++)
            Kt[((size_t)(bq * 12 + hh) * 1024 + tok) * 64 + n * 16 + fr]
                = (f16)(acc[m][n][i] * f);
        }
    } else {
      int hh = (hbase - 1536) >> 6;
      #pragma unroll
      for (int n = 0; n < 4; n++){
        int dd = n * 16 + fr;
        #pragma unroll
        for (int m = 0; m < 4; m++){
          int row0 = brow + m2 * 64 + m * 16 + (fq << 2);
          int bq = row0 >> 10, tok0 = row0 & 1023;
          ushort4 sv;
          sv.x = h2u((f16)acc[m][n][0]); sv.y = h2u((f16)acc[m][n][1]);
          sv.z = h2u((f16)acc[m][n][2]); sv.w = h2u((f16)acc[m][n][3]);
          *(ushort4*)(Vt + ((size_t)((bq * 12 + hh) * 64 + dd)) * 1024 + tok0) = sv;
        }
      }
    }
  } else if (mode == 1){
    #pragma unroll
    for (int n = 0; n < 4; n++){
      int col = bcol + n2 * 64 + n * 16 + fr;
      float bv = bias[col];
      #pragma unroll
      for (int m = 0; m < 4; m++){
        int row0 = brow + m2 * 64 + m * 16 + (fq << 2);
        #pragma unroll
        for (int i = 0; i < 4; i++){
          float v = acc[m][n][i] + bv;
          float ge = 0.5f * v * (1.f + erff(v * 0.70710678118654752f));
          Cq[(size_t)(row0 + i) * N + col] = (f16)ge;
        }
      }
    }
  } else {  // mode 3: f16 split-K partials
    f16* P = Cq + (size_t)bz * ((size_t)NTOK * N);
    #pragma unroll
    for (int n = 0; n < 4; n++){
      int col = bcol + n2 * 64 + n * 16 + fr;
      #pragma unroll
      for (int m = 0; m < 4; m++){
        int row0 = brow + m2 * 64 + m * 16 + (fq << 2);
        #pragma unroll
        for (int i = 0; i < 4; i++)
          P[(size_t)(row0 + i) * N + col] = (f16)acc[m][n][i];
      }
    }
  }
}

__global__ __launch_bounds__(256) void gemm_big(
    const f16* __restrict__ Aq, const f16* __restrict__ Bw,
    const float* __restrict__ bias,
    f16* __restrict__ Cq,
    f16* __restrict__ Qh, f16* __restrict__ Kt, f16* __restrict__ Vt,
    const float* __restrict__ qgam, const float* __restrict__ kgam,
    int N, int K, int nbx, int mode)
{
  gemm_big_body(blockIdx.x, blockIdx.z, (int)gridDim.z,
                Aq, Bw, bias, Cq, Qh, Kt, Vt, qgam, kgam, N, K, nbx, mode);
}

// ------ merged: qkv projection (blocks 0-287) + next-layer convert (288+) ----
__global__ __launch_bounds__(256) void qkvconv_kernel(
    const f16* __restrict__ Aq, const f16* __restrict__ Bw,
    f16* __restrict__ Qh, f16* __restrict__ Kt, f16* __restrict__ Vt,
    const float* __restrict__ qgam, const float* __restrict__ kgam,
    const float* __restrict__ Wq, const float* __restrict__ Wkv,
    const float* __restrict__ Wo, const float* __restrict__ W1,
    const float* __restrict__ W2, int nlayer, f16* __restrict__ thn)
{
  if (blockIdx.x < 288)
    gemm_big_body((int)blockIdx.x, 0, 1, Aq, Bw, nullptr, nullptr,
                  Qh, Kt, Vt, qgam, kgam, 3 * DIM, DIM, 18, 2);
  else if (nlayer >= 0)
    convert_body((int)blockIdx.x - 288, Wq, Wkv, Wo, W1, W2, nlayer, 0, thn);
}

// ------- small GEMM (64x64 block, 4 waves of 32x32, BK=128 single-buf) -------
__global__ __launch_bounds__(256) void gemm_small(
    const f16* __restrict__ Aq, const f16* __restrict__ Bw,
    const float* __restrict__ bias, const float* __restrict__ res,
    float* __restrict__ C, int N, int K, int nbx)
{
  __shared__ __align__(16) f16 sA[64 * 128];
  __shared__ __align__(16) f16 sB[64 * 128];
  const int tid = threadIdx.x;
  const int wid = tid >> 6, lane = tid & 63;
  const int nwg = nbx << 5;
  const int bid = blockIdx.x;
  const int swz = (bid & 7) * (nwg >> 3) + (bid >> 3);
  const int by = swz & 31, bx = swz >> 5;
  const int brow = by << 6, bcol = bx << 6;
  const int m2 = wid & 1, n2 = wid >> 1;
  const int fr = lane & 15, fq = lane >> 4;
  const int nk = K >> 7;

  const f16* pA = Aq + (size_t)brow * K;
  const f16* pB = Bw + (size_t)bcol * K;

  f32x4 acc[2][2] = {};

  for (int ks = 0; ks < nk; ks++){
    const int k0 = ks << 7;
    if (ks) __syncthreads();
    #pragma unroll
    for (int i = 0; i < 4; i++){
      int idx = tid + i * 256;
      int r = idx >> 4, c = idx & 15;
      int gc = c ^ (r & 7);
      gload16(pA + (size_t)r * K + k0 + gc * 8, &sA[idx * 8]);
      gload16(pB + (size_t)r * K + k0 + gc * 8, &sB[idx * 8]);
    }
    __syncthreads();
    #pragma unroll
    for (int s = 0; s < 4; s++){
      f16x8 a[2], b[2];
      #pragma unroll
      for (int m = 0; m < 2; m++){
        int r = m2 * 32 + m * 16 + fr;
        int ch = (s * 4 + fq) ^ (r & 7);
        a[m] = *(const f16x8*)(&sA[r * 128 + ch * 8]);
      }
      #pragma unroll
      for (int n = 0; n < 2; n++){
        int r = n2 * 32 + n * 16 + fr;
        int ch = (s * 4 + fq) ^ (r & 7);
        b[n] = *(const f16x8*)(&sB[r * 128 + ch * 8]);
      }
      #pragma unroll
      for (int m = 0; m < 2; m++)
        #pragma unroll
        for (int n = 0; n < 2; n++)
          acc[m][n] = __builtin_amdgcn_mfma_f32_16x16x32_f16(a[m], b[n], acc[m][n], 0, 0, 0);
    }
  }

  #pragma unroll
  for (int n = 0; n < 2; n++){
    int col = bcol + n2 * 32 + n * 16 + fr;
    float bv = bias ? bias[col] : 0.f;
    #pragma unroll
    for (int m = 0; m < 2; m++){
      int row0 = brow + m2 * 32 + m * 16 + (fq << 2);
      #pragma unroll
      for (int i = 0; i < 4; i++){
        float v = acc[m][n][i] + bv;
        size_t o = (size_t)(row0 + i) * N + col;
        if (res) v += res[o];
        C[o] = v;
      }
    }
  }
}

// ------- fused (optional 4-way f16 split-K reduce + badd + residual) + LN ----
__global__ __launch_bounds__(256) void lnred_kernel(
    float* __restrict__ x, const f16* __restrict__ p, const float* __restrict__ badd,
    int npart, const float* __restrict__ g, f16* __restrict__ yq, float* __restrict__ yf)
{
  int wid = threadIdx.x >> 6, lane = threadIdx.x & 63;
  int row = blockIdx.x * 4 + wid;
  float* xr = x + (size_t)row * DIM;
  float v[12]; float s = 0.f;
  if (npart){
    #pragma unroll
    for (int d = 0; d < 12; d++){
      int c = d * 64 + lane;
      float t = xr[c] + badd[c];
      #pragma unroll
      for (int j = 0; j < 4; j++)
        t += (float)p[(size_t)j * (NTOK * DIM) + (size_t)row * DIM + c];
      xr[c] = t; v[d] = t; s += t;
    }
  } else {
    #pragma unroll
    for (int d = 0; d < 12; d++){ v[d] = xr[d * 64 + lane]; s += v[d]; }
  }
  s = wred_sum(s);
  float mean = s * (1.f / 768.f);
  float q2 = 0.f;
  #pragma unroll
  for (int d = 0; d < 12; d++){ float t = v[d] - mean; q2 += t * t; }
  q2 = wred_sum(q2);
  float rstd = rsqrtf(q2 * (1.f / 768.f) + 1e-5f);
  size_t base = (size_t)row * DIM;
  #pragma unroll
  for (int d = 0; d < 12; d++){
    float y = (v[d] - mean) * rstd * g[d * 64 + lane];
    if (yq) yq[base + d * 64 + lane] = (f16)y;
    else    yf[base + d * 64 + lane] = y;
  }
}

// ---------------- pos-embed add -> f16 ---------------------------------------
__global__ __launch_bounds__(256) void posadd_kernel(
    const float* __restrict__ patches, const int* __restrict__ hi,
    const int* __restrict__ wi, const float* __restrict__ ph,
    const float* __restrict__ pw, f16* __restrict__ oq)
{
  int idx = blockIdx.x * 256 + threadIdx.x;
  int tok = idx / 192, cv = idx % 192;
  float4 p = ((const float4*)patches)[idx];
  float4 a = *(const float4*)(ph + (size_t)hi[tok] * DIM + cv * 4);
  float4 b = *(const float4*)(pw + (size_t)wi[tok] * DIM + cv * 4);
  ushort4 o;
  o.x = h2u((f16)(p.x + a.x + b.x)); o.y = h2u((f16)(p.y + a.y + b.y));
  o.z = h2u((f16)(p.z + a.z + b.z)); o.w = h2u((f16)(p.w + a.w + b.w));
  ((ushort4*)oq)[idx] = o;
}

// ---------------- segment ranges from sorted image_ids -----------------------
__global__ void seg_kernel(const int* __restrict__ ids, int2* __restrict__ segs)
{
  int i = blockIdx.x * 256 + threadIdx.x;
  int b = blockIdx.y;
  const int* row = ids + b * SEQ;
  int v = row[i];
  int lo = 0, hi = SEQ;
  while (lo < hi){ int mid = (lo + hi) >> 1; if (row[mid] <  v) lo = mid + 1; else hi = mid; }
  int s = lo;
  lo = 0; hi = SEQ;
  while (lo < hi){ int mid = (lo + hi) >> 1; if (row[mid] <= v) lo = mid + 1; else hi = mid; }
  segs[b * SEQ + i] = make_int2(s, lo);
}

// --------- MFMA flash attention over segments (all-f16, KVBLK=64) ------------
__global__ __launch_bounds__(256) void attn_kernel(
    const f16* __restrict__ qh, const f16* __restrict__ ktp,
    const f16* __restrict__ vt, const int2* __restrict__ segs,
    f16* __restrict__ oq)
{
  __shared__ __align__(16) ushort_t Kq[64 * 64];    // 8 KB, XOR-swizzled rows
  __shared__ __align__(16) ushort_t Vl[64 * 72];    // 9 KB, [d][key] stride 144B

  const int tid = threadIdx.x;
  const int w = tid >> 6, lane = tid & 63;
  const int q15 = lane & 15, kg = lane >> 4;
  const int bh = blockIdx.y, b = bh / 12, h = bh % 12;
  const int qt = blockIdx.x;
  const int qrow = qt * 64 + w * 16 + q15;
  const size_t qtok = (size_t)b * SEQ + qrow;

  const f16* qp = qh + qtok * DIM + h * 64 + kg * 8;
  f16x8 qf[2];
  qf[0] = *(const f16x8*)(qp);
  qf[1] = *(const f16x8*)(qp + 32);

  const int2 se  = segs[qtok];
  const int2 se0 = segs[(size_t)b * SEQ + qt * 64];
  const int2 se1 = segs[(size_t)b * SEQ + qt * 64 + 63];
  const int klo = se0.x & ~63, khi = se1.y;

  float m = -3.0e38f, l = 0.f;
  f32x4 oacc[4] = {};

  const f16* kbase = ktp + (size_t)bh * 1024 * 64;
  const int vd = tid >> 2, vc0 = tid & 3;

  for (int kt0 = klo; kt0 < khi; kt0 += 64){
    #pragma unroll
    for (int i = 0; i < 2; i++){
      int idx = tid + i * 256;
      int r = idx >> 3, c = idx & 7;
      int gc = c ^ (r & 7);
      gload16(kbase + (size_t)(kt0 + r) * 64 + gc * 8, Kq + idx * 8);
    }
    #pragma unroll
    for (int p2 = 0; p2 < 2; p2++){
      int chunk = vc0 + p2 * 4;
      uint4 vv = *(const uint4*)(vt + ((size_t)bh * 64 + vd) * SEQ + kt0 + chunk * 8);
      *(uint4*)((char*)Vl + vd * 144 + chunk * 16) = vv;
    }
    __syncthreads();

    f32x4 s[4] = {};
    #pragma unroll
    for (int dh2 = 0; dh2 < 2; dh2++){
      #pragma unroll
      for (int khf = 0; khf < 4; khf++){
        int row = khf * 16 + q15;
        unsigned off = ((unsigned)row << 7) + ((unsigned)(dh2 * 4 + kg) << 4);
        off ^= (unsigned)(row & 7) << 4;
        f16x8 kf = *(const f16x8*)((const char*)Kq + off);
        s[khf] = __builtin_amdgcn_mfma_f32_16x16x32_f16(kf, qf[dh2], s[khf], 0, 0, 0);
      }
    }

    float p[16]; float tmax = -3.0e38f;
    #pragma unroll
    for (int khf = 0; khf < 4; khf++)
      #pragma unroll
      for (int i = 0; i < 4; i++){
        int key = kt0 + khf * 16 + kg * 4 + i;
        bool val = (key >= se.x) && (key < se.y);
        float sv = val ? s[khf][i] : -3.0e38f;
        p[khf * 4 + i] = sv;
        tmax = fmaxf(tmax, sv);
      }
    tmax = fmaxf(tmax, __shfl_xor(tmax, 16));
    tmax = fmaxf(tmax, __shfl_xor(tmax, 32));
    float mnew = fmaxf(m, tmax);
    float sc = __expf(m - mnew);
    float psum = 0.f;
    #pragma unroll
    for (int j = 0; j < 16; j++){
      float pv = (p[j] > -1.0e38f) ? __expf(p[j] - mnew) : 0.f;
      p[j] = pv; psum += pv;
    }
    psum += __shfl_xor(psum, 16);
    psum += __shfl_xor(psum, 32);
    l = l * sc + psum;
    m = mnew;
    #pragma unroll
    for (int dt = 0; dt < 4; dt++) oacc[dt] *= sc;

    int s0l = q15 + ((kg & 1) << 5);
    int s1l = s0l + 16;
    bool hih = kg >= 2;
    unsigned uA0 = pk2h(p[0],  p[1]),  uA1 = pk2h(p[2],  p[3]);
    unsigned uA2 = pk2h(p[4],  p[5]),  uA3 = pk2h(p[6],  p[7]);
    unsigned uB0 = pk2h(p[8],  p[9]),  uB1 = pk2h(p[10], p[11]);
    unsigned uB2 = pk2h(p[12], p[13]), uB3 = pk2h(p[14], p[15]);
    unsigned a0 = __shfl(uA0, s0l), b0 = __shfl(uA1, s0l);
    unsigned a1 = __shfl(uA0, s1l), b1 = __shfl(uA1, s1l);
    unsigned c0 = __shfl(uA2, s0l), d0 = __shfl(uA3, s0l);
    unsigned c1 = __shfl(uA2, s1l), d1 = __shfl(uA3, s1l);
    f16x8 pfA = __builtin_bit_cast(f16x8,
        make_uint4(hih ? c0 : a0, hih ? d0 : b0, hih ? c1 : a1, hih ? d1 : b1));
    unsigned e0 = __shfl(uB0, s0l), f0 = __shfl(uB1, s0l);
    unsigned e1 = __shfl(uB0, s1l), f1 = __shfl(uB1, s1l);
    unsigned g0 = __shfl(uB2, s0l), h0 = __shfl(uB3, s0l);
    unsigned g1 = __shfl(uB2, s1l), h1 = __shfl(uB3, s1l);
    f16x8 pfB = __builtin_bit_cast(f16x8,
        make_uint4(hih ? g0 : e0, hih ? h0 : f0, hih ? g1 : e1, hih ? h1 : f1));

    #pragma unroll
    for (int dt = 0; dt < 4; dt++){
      const char* vb = (const char*)Vl + (dt * 16 + q15) * 144 + kg * 16;
      f16x8 vfA = *(const f16x8*)vb;
      f16x8 vfB = *(const f16x8*)(vb + 64);
      oacc[dt] = __builtin_amdgcn_mfma_f32_16x16x32_f16(vfA, pfA, oacc[dt], 0, 0, 0);
      oacc[dt] = __builtin_amdgcn_mfma_f32_16x16x32_f16(vfB, pfB, oacc[dt], 0, 0, 0);
    }
    __syncthreads();
  }

  float rl = 1.f / l;
  size_t obase = qtok * DIM + h * 64;
  #pragma unroll
  for (int dt = 0; dt < 4; dt++){
    ushort4 hs;
    hs.x = h2u((f16)(oacc[dt][0] * rl)); hs.y = h2u((f16)(oacc[dt][1] * rl));
    hs.z = h2u((f16)(oacc[dt][2] * rl)); hs.w = h2u((f16)(oacc[dt][3] * rl));
    *(ushort4*)(oq + obase + dt * 16 + kg * 4) = hs;
  }
}

// ---------------- driver -----------------------------------------------------
extern "C" void kernel_launch(void* const* d_in, const int* in_sizes, int n_in,
                              void* d_out, int out_size, void* d_ws, size_t ws_size,
                              hipStream_t stream)
{
  const float* patches   = (const float*)d_in[0];
  const int*   h_idx     = (const int*)d_in[1];
  const int*   w_idx     = (const int*)d_in[2];
  const int*   image_ids = (const int*)d_in[3];
  const float* pos_h = (const float*)d_in[4];
  const float* pos_w = (const float*)d_in[5];
  const float* Wp  = (const float*)d_in[6];
  const float* bp  = (const float*)d_in[7];
  const float* lnp = (const float*)d_in[8];
  const float* ln1 = (const float*)d_in[9];
  const float* qg  = (const float*)d_in[10];
  const float* kg  = (const float*)d_in[11];
  const float* Wq  = (const float*)d_in[12];
  const float* Wkv = (const float*)d_in[13];
  const float* Wo  = (const float*)d_in[14];
  const float* ln2 = (const float*)d_in[15];
  const float* W1  = (const float*)d_in[16];
  const float* b1  = (const float*)d_in[17];
  const float* W2  = (const float*)d_in[18];
  const float* b2  = (const float*)d_in[19];
  const float* lnf = (const float*)d_in[20];
  float* out = (float*)d_out;

  char* w = (char*)d_ws;
  float* x = (float*)w;            w += (size_t)NTOK * DIM * 4;
  f16* pbufh = (f16*)w;            w += (size_t)4 * NTOK * DIM * 2;   // split-K partials / Wp weights
  f16* qh  = (f16*)w;              w += (size_t)NTOK * DIM * 2;
  f16* ktb = (f16*)w;              w += (size_t)NTOK * DIM * 2;
  f16* vtb = (f16*)w;              w += (size_t)NTOK * DIM * 2;
  f16* aAq = (f16*)w;              w += (size_t)NTOK * DIM * 2;
  f16* aBq = (f16*)w;              w += (size_t)NTOK * MLP_ * 2;      // also f32 tmp
  int2* segs = (int2*)w;           w += (size_t)NTOK * 8;
  f16* wlA = (f16*)w;              w += (size_t)WELTS * 2;            // alternating hot
  f16* wlB = (f16*)w;                                                  // weight buffers
  float* ptmp = (float*)aBq;       // 2048*768 f32 fits in aBq region
  f16* wpc = pbufh;                // Wp converted (1.2MB) — dead until first W2

  seg_kernel<<<dim3(4, 2), 256, 0, stream>>>(image_ids, segs);
  posadd_kernel<<<1536, 256, 0, stream>>>(patches, h_idx, w_idx, pos_h, pos_w, aAq);
  convert_w_kernel<<<144, 256, 0, stream>>>(Wp, nullptr, nullptr, nullptr, nullptr, 0, 1, wpc);
  gemm_small<<<384, 256, 0, stream>>>(aAq, wpc, bp, nullptr, ptmp, DIM, DIM, 12);
  lnred_kernel<<<NTOK / 4, 256, 0, stream>>>(ptmp, nullptr, nullptr, 0, lnp, nullptr, x);
  convert_w_kernel<<<1728, 256, 0, stream>>>(Wq, Wkv, Wo, W1, W2, 0, 0, wlA);

  for (int i = 0; i < 8; i++){
    f16* wcur = (i & 1) ? wlB : wlA;
    f16* wnxt = (i & 1) ? wlA : wlB;
    // fused: x += (prev-layer W2 partials + b2) ; ln1 -> aAq (f16)
    lnred_kernel<<<NTOK / 4, 256, 0, stream>>>(
        x, pbufh, i ? (b2 + (i - 1) * DIM) : nullptr, i ? 4 : 0,
        ln1 + i * DIM, aAq, nullptr);
    // merged: qkv projection (+fused rmsnorm) || next-layer weight convert
    qkvconv_kernel<<<2016, 256, 0, stream>>>(
        aAq, wcur, qh, ktb, vtb, qg + i * DIM, kg + i * DIM,
        Wq, Wkv, Wo, W1, W2, (i < 7) ? i + 1 : -1, wnxt);
    attn_kernel<<<dim3(16, 24), 256, 0, stream>>>(qh, ktb, vtb, segs, aAq);
    gemm_small<<<384, 256, 0, stream>>>(
        aAq, wcur + 1769472, nullptr, x, x, DIM, DIM, 12);
    lnred_kernel<<<NTOK / 4, 256, 0, stream>>>(
        x, nullptr, nullptr, 0, ln2 + i * DIM, aAq, nullptr);
    gemm_big<<<384, 256, 0, stream>>>(
        aAq, wcur + 2359296, b1 + i * MLP_, aBq, nullptr, nullptr, nullptr,
        nullptr, nullptr, MLP_, DIM, 24, 1);
    gemm_big<<<dim3(96, 1, 4), 256, 0, stream>>>(
        aBq, wcur + 4718592, nullptr, pbufh, nullptr, nullptr, nullptr,
        nullptr, nullptr, DIM, MLP_, 6, 3);
  }
  lnred_kernel<<<NTOK / 4, 256, 0, stream>>>(x, pbufh, b2 + 7 * DIM, 4, lnf, nullptr, out);
}

// Round 18
// 867.761 us; speedup vs baseline: 1.4344x; 1.0060x over previous
//
#include <hip/hip_runtime.h>
#include <hip/hip_bf16.h>
#include <math.h>

typedef _Float16 f16;
typedef f16   f16x8 __attribute__((ext_vector_type(8)));
typedef float f32x4 __attribute__((ext_vector_type(4)));
typedef unsigned short ushort_t;

#define DIM   768
#define HEADS 12
#define DH    64
#define MLP_  3072
#define NTOK  2048
#define SEQ   1024
#define WELTS 7077888   // per-layer converted weight elements (Wq+Wkv+Wo+W1+W2)

__device__ __forceinline__ ushort_t h2u(f16 h){ return __builtin_bit_cast(ushort_t, h); }
__device__ __forceinline__ unsigned pk2h(float a, float b){
  return (unsigned)h2u((f16)a) | ((unsigned)h2u((f16)b) << 16);
}
__device__ __forceinline__ void gload16(const void* g, void* l){
  __builtin_amdgcn_global_load_lds(
      (const __attribute__((address_space(1))) void*)g,
      (__attribute__((address_space(3))) void*)l, 16, 0, 0);
}
__device__ __forceinline__ float wred_sum(float v){
  #pragma unroll
  for (int o = 32; o > 0; o >>= 1) v += __shfl_xor(v, o);
  return v;
}

// ---------- weight convert body: W[K][N] f32 -> Wt [N][K] f16 ----------------
__device__ __forceinline__ void convert_body(
    int bid, const float* __restrict__ Wq, const float* __restrict__ Wkv,
    const float* __restrict__ Wo, const float* __restrict__ W1,
    const float* __restrict__ W2, int layer, int wp_only,
    f16* __restrict__ th)
{
  const float* src; int K, N; size_t ooff; int t;
  if (wp_only){ src = Wq; K = 768; N = 768; ooff = 0; t = bid; }
  else if (bid < 144) { src = Wq;  K = 768;  N = 768;  ooff = 0;       t = bid; }
  else if (bid < 432) { src = Wkv; K = 768;  N = 1536; ooff = 589824;  t = bid - 144; }
  else if (bid < 576) { src = Wo;  K = 768;  N = 768;  ooff = 1769472; t = bid - 432; }
  else if (bid < 1152){ src = W1;  K = 768;  N = 3072; ooff = 2359296; t = bid - 576; }
  else                { src = W2;  K = 3072; N = 768;  ooff = 4718592; t = bid - 1152; }
  if (!wp_only) src += (size_t)layer * K * N;
  int ntn = N >> 6;
  int tk = t / ntn, tn = t % ntn;
  int k0 = tk * 64, n0 = tn * 64;

  __shared__ unsigned lp[32][66];
  const int tid = threadIdx.x;
  #pragma unroll
  for (int p = 0; p < 2; p++){
    int rp = p * 16 + (tid >> 4);
    int c  = (tid & 15) * 4;
    const float* s0 = src + (size_t)(k0 + 2 * rp) * N + n0 + c;
    float4 a = *(const float4*)s0;
    float4 b = *(const float4*)(s0 + N);
    unsigned u0 = pk2h(a.x, b.x), u1 = pk2h(a.y, b.y);
    unsigned u2 = pk2h(a.z, b.z), u3 = pk2h(a.w, b.w);
    *(uint4*)&lp[rp][c] = make_uint4(u0, u1, u2, u3);
  }
  __syncthreads();
  #pragma unroll
  for (int p = 0; p < 2; p++){
    int n = p * 32 + (tid >> 3);
    int q = tid & 7;
    unsigned u[4];
    #pragma unroll
    for (int j = 0; j < 4; j++) u[j] = lp[q * 4 + j][n];
    *(uint4*)(th + ooff + (size_t)(n0 + n) * K + k0 + q * 8)
        = make_uint4(u[0], u[1], u[2], u[3]);
  }
}

__global__ __launch_bounds__(256) void convert_w_kernel(
    const float* __restrict__ Wq, const float* __restrict__ Wkv,
    const float* __restrict__ Wo, const float* __restrict__ W1,
    const float* __restrict__ W2, int layer, int wp_only,
    f16* __restrict__ th)
{
  convert_body(blockIdx.x, Wq, Wkv, Wo, W1, W2, layer, wp_only, th);
}

// ---------------- pos-embed add body -> f16 ----------------------------------
__device__ __forceinline__ void posadd_body(
    int bid, const float* __restrict__ patches, const int* __restrict__ hi,
    const int* __restrict__ wi, const float* __restrict__ ph,
    const float* __restrict__ pw, f16* __restrict__ oq)
{
  int idx = bid * 256 + threadIdx.x;
  int tok = idx / 192, cv = idx % 192;
  float4 p = ((const float4*)patches)[idx];
  float4 a = *(const float4*)(ph + (size_t)hi[tok] * DIM + cv * 4);
  float4 b = *(const float4*)(pw + (size_t)wi[tok] * DIM + cv * 4);
  ushort4 o;
  o.x = h2u((f16)(p.x + a.x + b.x)); o.y = h2u((f16)(p.y + a.y + b.y));
  o.z = h2u((f16)(p.z + a.z + b.z)); o.w = h2u((f16)(p.w + a.w + b.w));
  ((ushort4*)oq)[idx] = o;
}

// ---------------- segment ranges body (sorted image_ids) ---------------------
__device__ __forceinline__ void seg_body(int bid, const int* __restrict__ ids,
                                         int2* __restrict__ segs)
{
  int i = (bid & 3) * 256 + threadIdx.x;
  int b = bid >> 2;
  const int* row = ids + b * SEQ;
  int v = row[i];
  int lo = 0, hi = SEQ;
  while (lo < hi){ int mid = (lo + hi) >> 1; if (row[mid] <  v) lo = mid + 1; else hi = mid; }
  int s = lo;
  lo = 0; hi = SEQ;
  while (lo < hi){ int mid = (lo + hi) >> 1; if (row[mid] <= v) lo = mid + 1; else hi = mid; }
  segs[b * SEQ + i] = make_int2(s, lo);
}

// ------ merged prologue: posadd (0..1535) | convert Wp (1536..1679) |
//        convert layer0 (1680..3407) | seg (3408..3415) ----------------------
__global__ __launch_bounds__(256) void prologue_kernel(
    const float* __restrict__ patches, const int* __restrict__ hi,
    const int* __restrict__ wi, const float* __restrict__ ph,
    const float* __restrict__ pw, f16* __restrict__ oq,
    const float* __restrict__ Wp, f16* __restrict__ wpc,
    const float* __restrict__ Wq, const float* __restrict__ Wkv,
    const float* __restrict__ Wo, const float* __restrict__ W1,
    const float* __restrict__ W2, f16* __restrict__ wl0,
    const int* __restrict__ ids, int2* __restrict__ segs)
{
  int bid = blockIdx.x;
  if (bid < 1536)      posadd_body(bid, patches, hi, wi, ph, pw, oq);
  else if (bid < 1680) convert_body(bid - 1536, Wp, nullptr, nullptr, nullptr,
                                    nullptr, 0, 1, wpc);
  else if (bid < 3408) convert_body(bid - 1680, Wq, Wkv, Wo, W1, W2, 0, 0, wl0);
  else                 seg_body(bid - 3408, ids, segs);
}

// ------------- big GEMM body: 128x128 block, 4 waves of 64x64, BK=128 --------
// single-buffer LDS (64KB), XOR-swizzled via pre-swizzled global_load_lds src;
// halved K-steps amortize the per-step barrier drain (grid-limited occupancy).
// mode 1: f16 gelu(acc+bias) -> Cq[N]
// mode 2: qkv epilogue (fused qk-rmsnorm, gammas folded into Q)
// mode 3: split-K f16 partial -> Cq + z*NTOK*N
__device__ __forceinline__ void gemm_big_body(
    int bid, int bz, int nz,
    const f16* __restrict__ Aq, const f16* __restrict__ Bw,
    const float* __restrict__ bias,
    f16* __restrict__ Cq,
    f16* __restrict__ Qh, f16* __restrict__ Kt, f16* __restrict__ Vt,
    const float* __restrict__ qgam, const float* __restrict__ kgam,
    int N, int K, int nbx, int mode)
{
  __shared__ __align__(16) f16 sA[128 * 128];
  __shared__ __align__(16) f16 sB[128 * 128];
  const int tid = threadIdx.x;
  const int wid = tid >> 6, lane = tid & 63;
  const int nwg = nbx << 4;
  const int swz = (bid & 7) * (nwg >> 3) + (bid >> 3);
  const int by = swz & 15, bx = swz >> 4;
  const int brow = by << 7, bcol = bx << 7;
  const int m2 = wid & 1, n2 = wid >> 1;
  const int fr = lane & 15, fq = lane >> 4;
  const int Kc = K / nz;
  const int kbase = bz * Kc;
  const int nk = Kc >> 7;

  const f16* pA = Aq + (size_t)brow * K + kbase;
  const f16* pB = Bw + (size_t)bcol * K + kbase;

  f32x4 acc[4][4] = {};

  for (int ks = 0; ks < nk; ks++){
    const int k0 = ks << 7;
    if (ks) __syncthreads();
    #pragma unroll
    for (int i = 0; i < 8; i++){
      int idx = tid + i * 256;
      int r = idx >> 4, c = idx & 15;
      int gc = c ^ (r & 7);
      gload16(pA + (size_t)r * K + k0 + gc * 8, &sA[idx * 8]);
      gload16(pB + (size_t)r * K + k0 + gc * 8, &sB[idx * 8]);
    }
    __syncthreads();
    #pragma unroll
    for (int s = 0; s < 4; s++){
      f16x8 a[4], b[4];
      #pragma unroll
      for (int m = 0; m < 4; m++){
        int r = m2 * 64 + m * 16 + fr;
        int ch = (s * 4 + fq) ^ (r & 7);
        a[m] = *(const f16x8*)(&sA[r * 128 + ch * 8]);
      }
      #pragma unroll
      for (int n = 0; n < 4; n++){
        int r = n2 * 64 + n * 16 + fr;
        int ch = (s * 4 + fq) ^ (r & 7);
        b[n] = *(const f16x8*)(&sB[r * 128 + ch * 8]);
      }
      #pragma unroll
      for (int m = 0; m < 4; m++)
        #pragma unroll
        for (int n = 0; n < 4; n++)
          acc[m][n] = __builtin_amdgcn_mfma_f32_16x16x32_f16(a[m], b[n], acc[m][n], 0, 0, 0);
    }
  }

  // epilogue: D layout col=lane&15, row=(lane>>4)*4+i
  if (mode == 2){
    const int hbase = bcol + n2 * 64;   // wave-uniform, 64-aligned head block
    if (hbase < 768){
      float gp[4];
      #pragma unroll
      for (int n = 0; n < 4; n++){
        int col = hbase + n * 16 + fr;
        gp[n] = qgam[col] * kgam[col];
      }
      #pragma unroll
      for (int m = 0; m < 4; m++)
        #pragma unroll
        for (int i = 0; i < 4; i++){
          float s = 0.f;
          #pragma unroll
          for (int n = 0; n < 4; n++) s += acc[m][n][i] * acc[m][n][i];
          s += __shfl_xor(s, 1); s += __shfl_xor(s, 2);
          s += __shfl_xor(s, 4); s += __shfl_xor(s, 8);
          float f = 8.f / fmaxf(sqrtf(s), 1e-12f);
          int row = brow + m2 * 64 + m * 16 + (fq << 2) + i;
          #pragma unroll
          for (int n = 0; n < 4; n++)
            Qh[(size_t)row * 768 + hbase + n * 16 + fr] = (f16)(acc[m][n][i] * f * gp[n]);
        }
    } else if (hbase < 1536){
      int hh = (hbase - 768) >> 6;
      #pragma unroll
      for (int m = 0; m < 4; m++)
        #pragma unroll
        for (int i = 0; i < 4; i++){
          float s = 0.f;
          #pragma unroll
          for (int n = 0; n < 4; n++) s += acc[m][n][i] * acc[m][n][i];
          s += __shfl_xor(s, 1); s += __shfl_xor(s, 2);
          s += __shfl_xor(s, 4); s += __shfl_xor(s, 8);
          float f = 8.f / fmaxf(sqrtf(s), 1e-12f);
          int row = brow + m2 * 64 + m * 16 + (fq << 2) + i;
          int bq = row >> 10, tok = row & 1023;
          #pragma unroll
          for (int n = 0; n < 4; n++)
            Kt[((size_t)(bq * 12 + hh) * 1024 + tok) * 64 + n * 16 + fr]
                = (f16)(acc[m][n][i] * f);
        }
    } else {
      int hh = (hbase - 1536) >> 6;
      #pragma unroll
      for (int n = 0; n < 4; n++){
        int dd = n * 16 + fr;
        #pragma unroll
        for (int m = 0; m < 4; m++){
          int row0 = brow + m2 * 64 + m * 16 + (fq << 2);
          int bq = row0 >> 10, tok0 = row0 & 1023;
          ushort4 sv;
          sv.x = h2u((f16)acc[m][n][0]); sv.y = h2u((f16)acc[m][n][1]);
          sv.z = h2u((f16)acc[m][n][2]); sv.w = h2u((f16)acc[m][n][3]);
          *(ushort4*)(Vt + ((size_t)((bq * 12 + hh) * 64 + dd)) * 1024 + tok0) = sv;
        }
      }
    }
  } else if (mode == 1){
    #pragma unroll
    for (int n = 0; n < 4; n++){
      int col = bcol + n2 * 64 + n * 16 + fr;
      float bv = bias[col];
      #pragma unroll
      for (int m = 0; m < 4; m++){
        int row0 = brow + m2 * 64 + m * 16 + (fq << 2);
        #pragma unroll
        for (int i = 0; i < 4; i++){
          float v = acc[m][n][i] + bv;
          float ge = 0.5f * v * (1.f + erff(v * 0.70710678118654752f));
          Cq[(size_t)(row0 + i) * N + col] = (f16)ge;
        }
      }
    }
  } else {  // mode 3: f16 split-K partials
    f16* P = Cq + (size_t)bz * ((size_t)NTOK * N);
    #pragma unroll
    for (int n = 0; n < 4; n++){
      int col = bcol + n2 * 64 + n * 16 + fr;
      #pragma unroll
      for (int m = 0; m < 4; m++){
        int row0 = brow + m2 * 64 + m * 16 + (fq << 2);
        #pragma unroll
        for (int i = 0; i < 4; i++)
          P[(size_t)(row0 + i) * N + col] = (f16)acc[m][n][i];
      }
    }
  }
}

__global__ __launch_bounds__(256) void gemm_big(
    const f16* __restrict__ Aq, const f16* __restrict__ Bw,
    const float* __restrict__ bias,
    f16* __restrict__ Cq,
    f16* __restrict__ Qh, f16* __restrict__ Kt, f16* __restrict__ Vt,
    const float* __restrict__ qgam, const float* __restrict__ kgam,
    int N, int K, int nbx, int mode)
{
  gemm_big_body(blockIdx.x, blockIdx.z, (int)gridDim.z,
                Aq, Bw, bias, Cq, Qh, Kt, Vt, qgam, kgam, N, K, nbx, mode);
}

// ------ merged: qkv projection (blocks 0-287) + next-layer convert (288+) ----
__global__ __launch_bounds__(256) void qkvconv_kernel(
    const f16* __restrict__ Aq, const f16* __restrict__ Bw,
    f16* __restrict__ Qh, f16* __restrict__ Kt, f16* __restrict__ Vt,
    const float* __restrict__ qgam, const float* __restrict__ kgam,
    const float* __restrict__ Wq, const float* __restrict__ Wkv,
    const float* __restrict__ Wo, const float* __restrict__ W1,
    const float* __restrict__ W2, int nlayer, f16* __restrict__ thn)
{
  if (blockIdx.x < 288)
    gemm_big_body((int)blockIdx.x, 0, 1, Aq, Bw, nullptr, nullptr,
                  Qh, Kt, Vt, qgam, kgam, 3 * DIM, DIM, 18, 2);
  else if (nlayer >= 0)
    convert_body((int)blockIdx.x - 288, Wq, Wkv, Wo, W1, W2, nlayer, 0, thn);
}

// ------- small GEMM (64x64 block, 4 waves of 32x32, BK=128 single-buf) -------
__global__ __launch_bounds__(256) void gemm_small(
    const f16* __restrict__ Aq, const f16* __restrict__ Bw,
    const float* __restrict__ bias, const float* __restrict__ res,
    float* __restrict__ C, int N, int K, int nbx)
{
  __shared__ __align__(16) f16 sA[64 * 128];
  __shared__ __align__(16) f16 sB[64 * 128];
  const int tid = threadIdx.x;
  const int wid = tid >> 6, lane = tid & 63;
  const int nwg = nbx << 5;
  const int bid = blockIdx.x;
  const int swz = (bid & 7) * (nwg >> 3) + (bid >> 3);
  const int by = swz & 31, bx = swz >> 5;
  const int brow = by << 6, bcol = bx << 6;
  const int m2 = wid & 1, n2 = wid >> 1;
  const int fr = lane & 15, fq = lane >> 4;
  const int nk = K >> 7;

  const f16* pA = Aq + (size_t)brow * K;
  const f16* pB = Bw + (size_t)bcol * K;

  f32x4 acc[2][2] = {};

  for (int ks = 0; ks < nk; ks++){
    const int k0 = ks << 7;
    if (ks) __syncthreads();
    #pragma unroll
    for (int i = 0; i < 4; i++){
      int idx = tid + i * 256;
      int r = idx >> 4, c = idx & 15;
      int gc = c ^ (r & 7);
      gload16(pA + (size_t)r * K + k0 + gc * 8, &sA[idx * 8]);
      gload16(pB + (size_t)r * K + k0 + gc * 8, &sB[idx * 8]);
    }
    __syncthreads();
    #pragma unroll
    for (int s = 0; s < 4; s++){
      f16x8 a[2], b[2];
      #pragma unroll
      for (int m = 0; m < 2; m++){
        int r = m2 * 32 + m * 16 + fr;
        int ch = (s * 4 + fq) ^ (r & 7);
        a[m] = *(const f16x8*)(&sA[r * 128 + ch * 8]);
      }
      #pragma unroll
      for (int n = 0; n < 2; n++){
        int r = n2 * 32 + n * 16 + fr;
        int ch = (s * 4 + fq) ^ (r & 7);
        b[n] = *(const f16x8*)(&sB[r * 128 + ch * 8]);
      }
      #pragma unroll
      for (int m = 0; m < 2; m++)
        #pragma unroll
        for (int n = 0; n < 2; n++)
          acc[m][n] = __builtin_amdgcn_mfma_f32_16x16x32_f16(a[m], b[n], acc[m][n], 0, 0, 0);
    }
  }

  #pragma unroll
  for (int n = 0; n < 2; n++){
    int col = bcol + n2 * 32 + n * 16 + fr;
    float bv = bias ? bias[col] : 0.f;
    #pragma unroll
    for (int m = 0; m < 2; m++){
      int row0 = brow + m2 * 32 + m * 16 + (fq << 2);
      #pragma unroll
      for (int i = 0; i < 4; i++){
        float v = acc[m][n][i] + bv;
        size_t o = (size_t)(row0 + i) * N + col;
        if (res) v += res[o];
        C[o] = v;
      }
    }
  }
}

// ------- fused (optional 4-way f16 split-K reduce + badd + residual) + LN ----
__global__ __launch_bounds__(256) void lnred_kernel(
    float* __restrict__ x, const f16* __restrict__ p, const float* __restrict__ badd,
    int npart, const float* __restrict__ g, f16* __restrict__ yq, float* __restrict__ yf)
{
  int wid = threadIdx.x >> 6, lane = threadIdx.x & 63;
  int row = blockIdx.x * 4 + wid;
  float* xr = x + (size_t)row * DIM;
  float v[12]; float s = 0.f;
  if (npart){
    #pragma unroll
    for (int d = 0; d < 12; d++){
      int c = d * 64 + lane;
      float t = xr[c] + badd[c];
      #pragma unroll
      for (int j = 0; j < 4; j++)
        t += (float)p[(size_t)j * (NTOK * DIM) + (size_t)row * DIM + c];
      xr[c] = t; v[d] = t; s += t;
    }
  } else {
    #pragma unroll
    for (int d = 0; d < 12; d++){ v[d] = xr[d * 64 + lane]; s += v[d]; }
  }
  s = wred_sum(s);
  float mean = s * (1.f / 768.f);
  float q2 = 0.f;
  #pragma unroll
  for (int d = 0; d < 12; d++){ float t = v[d] - mean; q2 += t * t; }
  q2 = wred_sum(q2);
  float rstd = rsqrtf(q2 * (1.f / 768.f) + 1e-5f);
  size_t base = (size_t)row * DIM;
  #pragma unroll
  for (int d = 0; d < 12; d++){
    float y = (v[d] - mean) * rstd * g[d * 64 + lane];
    if (yq) yq[base + d * 64 + lane] = (f16)y;
    else    yf[base + d * 64 + lane] = y;
  }
}

// --------- MFMA flash attention over segments (all-f16, KVBLK=64) ------------
__global__ __launch_bounds__(256) void attn_kernel(
    const f16* __restrict__ qh, const f16* __restrict__ ktp,
    const f16* __restrict__ vt, const int2* __restrict__ segs,
    f16* __restrict__ oq)
{
  __shared__ __align__(16) ushort_t Kq[64 * 64];    // 8 KB, XOR-swizzled rows
  __shared__ __align__(16) ushort_t Vl[64 * 72];    // 9 KB, [d][key] stride 144B

  const int tid = threadIdx.x;
  const int w = tid >> 6, lane = tid & 63;
  const int q15 = lane & 15, kg = lane >> 4;
  const int bh = blockIdx.y, b = bh / 12, h = bh % 12;
  const int qt = blockIdx.x;
  const int qrow = qt * 64 + w * 16 + q15;
  const size_t qtok = (size_t)b * SEQ + qrow;

  const f16* qp = qh + qtok * DIM + h * 64 + kg * 8;
  f16x8 qf[2];
  qf[0] = *(const f16x8*)(qp);
  qf[1] = *(const f16x8*)(qp + 32);

  const int2 se  = segs[qtok];
  const int2 se0 = segs[(size_t)b * SEQ + qt * 64];
  const int2 se1 = segs[(size_t)b * SEQ + qt * 64 + 63];
  const int klo = se0.x & ~63, khi = se1.y;

  float m = -3.0e38f, l = 0.f;
  f32x4 oacc[4] = {};

  const f16* kbase = ktp + (size_t)bh * 1024 * 64;
  const int vd = tid >> 2, vc0 = tid & 3;

  for (int kt0 = klo; kt0 < khi; kt0 += 64){
    #pragma unroll
    for (int i = 0; i < 2; i++){
      int idx = tid + i * 256;
      int r = idx >> 3, c = idx & 7;
      int gc = c ^ (r & 7);
      gload16(kbase + (size_t)(kt0 + r) * 64 + gc * 8, Kq + idx * 8);
    }
    #pragma unroll
    for (int p2 = 0; p2 < 2; p2++){
      int chunk = vc0 + p2 * 4;
      uint4 vv = *(const uint4*)(vt + ((size_t)bh * 64 + vd) * SEQ + kt0 + chunk * 8);
      *(uint4*)((char*)Vl + vd * 144 + chunk * 16) = vv;
    }
    __syncthreads();

    f32x4 s[4] = {};
    #pragma unroll
    for (int dh2 = 0; dh2 < 2; dh2++){
      #pragma unroll
      for (int khf = 0; khf < 4; khf++){
        int row = khf * 16 + q15;
        unsigned off = ((unsigned)row << 7) + ((unsigned)(dh2 * 4 + kg) << 4);
        off ^= (unsigned)(row & 7) << 4;
        f16x8 kf = *(const f16x8*)((const char*)Kq + off);
        s[khf] = __builtin_amdgcn_mfma_f32_16x16x32_f16(kf, qf[dh2], s[khf], 0, 0, 0);
      }
    }

    float p[16]; float tmax = -3.0e38f;
    #pragma unroll
    for (int khf = 0; khf < 4; khf++)
      #pragma unroll
      for (int i = 0; i < 4; i++){
        int key = kt0 + khf * 16 + kg * 4 + i;
        bool val = (key >= se.x) && (key < se.y);
        float sv = val ? s[khf][i] : -3.0e38f;
        p[khf * 4 + i] = sv;
        tmax = fmaxf(tmax, sv);
      }
    tmax = fmaxf(tmax, __shfl_xor(tmax, 16));
    tmax = fmaxf(tmax, __shfl_xor(tmax, 32));
    float mnew = fmaxf(m, tmax);
    float sc = __expf(m - mnew);
    float psum = 0.f;
    #pragma unroll
    for (int j = 0; j < 16; j++){
      float pv = (p[j] > -1.0e38f) ? __expf(p[j] - mnew) : 0.f;
      p[j] = pv; psum += pv;
    }
    psum += __shfl_xor(psum, 16);
    psum += __shfl_xor(psum, 32);
    l = l * sc + psum;
    m = mnew;
    #pragma unroll
    for (int dt = 0; dt < 4; dt++) oacc[dt] *= sc;

    int s0l = q15 + ((kg & 1) << 5);
    int s1l = s0l + 16;
    bool hih = kg >= 2;
    unsigned uA0 = pk2h(p[0],  p[1]),  uA1 = pk2h(p[2],  p[3]);
    unsigned uA2 = pk2h(p[4],  p[5]),  uA3 = pk2h(p[6],  p[7]);
    unsigned uB0 = pk2h(p[8],  p[9]),  uB1 = pk2h(p[10], p[11]);
    unsigned uB2 = pk2h(p[12], p[13]), uB3 = pk2h(p[14], p[15]);
    unsigned a0 = __shfl(uA0, s0l), b0 = __shfl(uA1, s0l);
    unsigned a1 = __shfl(uA0, s1l), b1 = __shfl(uA1, s1l);
    unsigned c0 = __shfl(uA2, s0l), d0 = __shfl(uA3, s0l);
    unsigned c1 = __shfl(uA2, s1l), d1 = __shfl(uA3, s1l);
    f16x8 pfA = __builtin_bit_cast(f16x8,
        make_uint4(hih ? c0 : a0, hih ? d0 : b0, hih ? c1 : a1, hih ? d1 : b1));
    unsigned e0 = __shfl(uB0, s0l), f0 = __shfl(uB1, s0l);
    unsigned e1 = __shfl(uB0, s1l), f1 = __shfl(uB1, s1l);
    unsigned g0 = __shfl(uB2, s0l), h0 = __shfl(uB3, s0l);
    unsigned g1 = __shfl(uB2, s1l), h1 = __shfl(uB3, s1l);
    f16x8 pfB = __builtin_bit_cast(f16x8,
        make_uint4(hih ? g0 : e0, hih ? h0 : f0, hih ? g1 : e1, hih ? h1 : f1));

    #pragma unroll
    for (int dt = 0; dt < 4; dt++){
      const char* vb = (const char*)Vl + (dt * 16 + q15) * 144 + kg * 16;
      f16x8 vfA = *(const f16x8*)vb;
      f16x8 vfB = *(const f16x8*)(vb + 64);
      oacc[dt] = __builtin_amdgcn_mfma_f32_16x16x32_f16(vfA, pfA, oacc[dt], 0, 0, 0);
      oacc[dt] = __builtin_amdgcn_mfma_f32_16x16x32_f16(vfB, pfB, oacc[dt], 0, 0, 0);
    }
    __syncthreads();
  }

  float rl = 1.f / l;
  size_t obase = qtok * DIM + h * 64;
  #pragma unroll
  for (int dt = 0; dt < 4; dt++){
    ushort4 hs;
    hs.x = h2u((f16)(oacc[dt][0] * rl)); hs.y = h2u((f16)(oacc[dt][1] * rl));
    hs.z = h2u((f16)(oacc[dt][2] * rl)); hs.w = h2u((f16)(oacc[dt][3] * rl));
    *(ushort4*)(oq + obase + dt * 16 + kg * 4) = hs;
  }
}

// ---------------- driver -----------------------------------------------------
extern "C" void kernel_launch(void* const* d_in, const int* in_sizes, int n_in,
                              void* d_out, int out_size, void* d_ws, size_t ws_size,
                              hipStream_t stream)
{
  const float* patches   = (const float*)d_in[0];
  const int*   h_idx     = (const int*)d_in[1];
  const int*   w_idx     = (const int*)d_in[2];
  const int*   image_ids = (const int*)d_in[3];
  const float* pos_h = (const float*)d_in[4];
  const float* pos_w = (const float*)d_in[5];
  const float* Wp  = (const float*)d_in[6];
  const float* bp  = (const float*)d_in[7];
  const float* lnp = (const float*)d_in[8];
  const float* ln1 = (const float*)d_in[9];
  const float* qg  = (const float*)d_in[10];
  const float* kg  = (const float*)d_in[11];
  const float* Wq  = (const float*)d_in[12];
  const float* Wkv = (const float*)d_in[13];
  const float* Wo  = (const float*)d_in[14];
  const float* ln2 = (const float*)d_in[15];
  const float* W1  = (const float*)d_in[16];
  const float* b1  = (const float*)d_in[17];
  const float* W2  = (const float*)d_in[18];
  const float* b2  = (const float*)d_in[19];
  const float* lnf = (const float*)d_in[20];
  float* out = (float*)d_out;

  char* w = (char*)d_ws;
  float* x = (float*)w;            w += (size_t)NTOK * DIM * 4;
  f16* pbufh = (f16*)w;            w += (size_t)4 * NTOK * DIM * 2;   // split-K partials / Wp weights
  f16* qh  = (f16*)w;              w += (size_t)NTOK * DIM * 2;
  f16* ktb = (f16*)w;              w += (size_t)NTOK * DIM * 2;
  f16* vtb = (f16*)w;              w += (size_t)NTOK * DIM * 2;
  f16* aAq = (f16*)w;              w += (size_t)NTOK * DIM * 2;
  f16* aBq = (f16*)w;              w += (size_t)NTOK * MLP_ * 2;      // also f32 tmp
  int2* segs = (int2*)w;           w += (size_t)NTOK * 8;
  f16* wlA = (f16*)w;              w += (size_t)WELTS * 2;            // alternating hot
  f16* wlB = (f16*)w;                                                  // weight buffers
  float* ptmp = (float*)aBq;       // 2048*768 f32 fits in aBq region
  f16* wpc = pbufh;                // Wp converted (1.2MB) — dead until first W2

  // merged prologue: posadd | convert Wp | convert layer0 | seg
  prologue_kernel<<<3416, 256, 0, stream>>>(
      patches, h_idx, w_idx, pos_h, pos_w, aAq,
      Wp, wpc, Wq, Wkv, Wo, W1, W2, wlA, image_ids, segs);
  gemm_small<<<384, 256, 0, stream>>>(aAq, wpc, bp, nullptr, ptmp, DIM, DIM, 12);
  lnred_kernel<<<NTOK / 4, 256, 0, stream>>>(ptmp, nullptr, nullptr, 0, lnp, nullptr, x);

  for (int i = 0; i < 8; i++){
    f16* wcur = (i & 1) ? wlB : wlA;
    f16* wnxt = (i & 1) ? wlA : wlB;
    // fused: x += (prev-layer W2 partials + b2) ; ln1 -> aAq (f16)
    lnred_kernel<<<NTOK / 4, 256, 0, stream>>>(
        x, pbufh, i ? (b2 + (i - 1) * DIM) : nullptr, i ? 4 : 0,
        ln1 + i * DIM, aAq, nullptr);
    // merged: qkv projection (+fused rmsnorm) || next-layer weight convert
    qkvconv_kernel<<<2016, 256, 0, stream>>>(
        aAq, wcur, qh, ktb, vtb, qg + i * DIM, kg + i * DIM,
        Wq, Wkv, Wo, W1, W2, (i < 7) ? i + 1 : -1, wnxt);
    attn_kernel<<<dim3(16, 24), 256, 0, stream>>>(qh, ktb, vtb, segs, aAq);
    gemm_small<<<384, 256, 0, stream>>>(
        aAq, wcur + 1769472, nullptr, x, x, DIM, DIM, 12);
    lnred_kernel<<<NTOK / 4, 256, 0, stream>>>(
        x, nullptr, nullptr, 0, ln2 + i * DIM, aAq, nullptr);
    gemm_big<<<384, 256, 0, stream>>>(
        aAq, wcur + 2359296, b1 + i * MLP_, aBq, nullptr, nullptr, nullptr,
        nullptr, nullptr, MLP_, DIM, 24, 1);
    gemm_big<<<dim3(96, 1, 4), 256, 0, stream>>>(
        aBq, wcur + 4718592, nullptr, pbufh, nullptr, nullptr, nullptr,
        nullptr, nullptr, DIM, MLP_, 6, 3);
  }
  lnred_kernel<<<NTOK / 4, 256, 0, stream>>>(x, pbufh, b2 + 7 * DIM, 4, lnf, nullptr, out);
}